// Round 8
// baseline (691.332 us; speedup 1.0000x reference)
//
#include <hip/hip_runtime.h>
#include <hip/hip_bf16.h>

#define N_NODES 100000
#define N_EDGES 640000

typedef __bf16 bf16_t;
typedef __bf16 bf16x8 __attribute__((ext_vector_type(8)));
typedef float f32x4 __attribute__((ext_vector_type(4)));
typedef float f4 __attribute__((ext_vector_type(4)));
typedef unsigned int u32x4 __attribute__((ext_vector_type(4)));

// ---------------------------------------------------------------------------
// nodef f32 -> bf16 (25.6MB, cache-resident gather target)
// ---------------------------------------------------------------------------
__global__ __launch_bounds__(256)
void convert_nodef_kernel(const float* __restrict__ nodef,
                          unsigned short* __restrict__ nodef_bf) {
    int i = blockIdx.x * 256 + threadIdx.x;   // one float4 -> 4 bf16
    if (i < N_NODES * 32) {
        f4 v = *reinterpret_cast<const f4*>(nodef + (size_t)i * 4);
        union { bf16_t b[4]; unsigned long long ll; } pk;
        pk.b[0] = (bf16_t)v[0]; pk.b[1] = (bf16_t)v[1];
        pk.b[2] = (bf16_t)v[2]; pk.b[3] = (bf16_t)v[3];
        *reinterpret_cast<unsigned long long*>(nodef_bf + (size_t)i * 4) = pk.ll;
    }
}

// ---------------------------------------------------------------------------
// Prep: transpose + convert weights to bf16.
//   WtAB [256][384]: rows 0..127 = W_msg columns, rows 128..255 = W_rev columns
//   WtU  [128][128]: WtU[n][p] = W_upd[pi(p)][n], pi = msgs stored-column perm
// ---------------------------------------------------------------------------
__global__ void prep_weights_kernel(const float* __restrict__ Wmsg,
                                    const float* __restrict__ Wrev,
                                    const float* __restrict__ Wupd,
                                    bf16_t* __restrict__ WtAB,
                                    bf16_t* __restrict__ WtU) {
    int idx = blockIdx.x * 256 + threadIdx.x;
    if (idx < 256 * 384) {
        int n = idx / 384;
        int k = idx - n * 384;
        float v = (n < 128) ? Wmsg[k * 128 + n] : Wrev[k * 128 + (n - 128)];
        WtAB[idx] = (bf16_t)v;
    }
    if (idx < 128 * 128) {
        int n = idx >> 7;
        int p = idx & 127;
        int colp = 32 * (p >> 5) + ((p >> 1) & 15) + 16 * (p & 1);
        WtU[idx] = (bf16_t)Wupd[colp * 128 + n];
    }
}

// ---------------------------------------------------------------------------
// CSR build: hist -> hierarchical scan (coalesced) -> inverse permutation.
// ---------------------------------------------------------------------------
__global__ void hist_kernel(const int* __restrict__ to_idx, int* __restrict__ hist) {
    int e = blockIdx.x * 256 + threadIdx.x;
    if (e < N_EDGES) atomicAdd(&hist[to_idx[e]], 1);
}

#define SCAN_CH 1000  // N_NODES = 100 blocks x 1000

__global__ __launch_bounds__(1024)
void scan_reduce_kernel(const int* __restrict__ hist, int* __restrict__ bsum) {
    __shared__ int red[1024];
    int b = blockIdx.x, t = threadIdx.x;
    int v = (t < SCAN_CH) ? hist[b * SCAN_CH + t] : 0;
    red[t] = v;
    __syncthreads();
    for (int off = 512; off > 0; off >>= 1) {
        if (t < off) red[t] += red[t + off];
        __syncthreads();
    }
    if (t == 0) bsum[b] = red[0];
}

__global__ __launch_bounds__(128)
void scan_base_kernel(const int* __restrict__ bsum, int* __restrict__ bbase) {
    __shared__ int s[128];
    int t = threadIdx.x;
    int v = (t < 100) ? bsum[t] : 0;
    s[t] = v;
    __syncthreads();
    for (int off = 1; off < 128; off <<= 1) {
        int u = (t >= off) ? s[t - off] : 0;
        __syncthreads();
        s[t] += u;
        __syncthreads();
    }
    if (t < 100) bbase[t] = s[t] - v;  // exclusive base per block
}

__global__ __launch_bounds__(1024)
void scan_final_kernel(const int* __restrict__ hist,
                       const int* __restrict__ bbase,
                       int* __restrict__ cursor,
                       int* __restrict__ row_start) {
    __shared__ int s[1024];
    int b = blockIdx.x, t = threadIdx.x;
    int v = (t < SCAN_CH) ? hist[b * SCAN_CH + t] : 0;
    s[t] = v;
    __syncthreads();
    for (int off = 1; off < 1024; off <<= 1) {
        int u = (t >= off) ? s[t - off] : 0;
        __syncthreads();
        s[t] += u;
        __syncthreads();
    }
    int excl = bbase[b] + s[t] - v;
    if (t < SCAN_CH) {
        cursor[b * SCAN_CH + t] = excl;
        row_start[b * SCAN_CH + t] = excl;
    }
    if (b == 99 && t == SCAN_CH - 1) row_start[N_NODES] = excl + v;  // = N_EDGES
}

__global__ void inv_scatter_kernel(const int* __restrict__ to_idx,
                                   int* __restrict__ cursor,
                                   int* __restrict__ inv) {
    int e = blockIdx.x * 256 + threadIdx.x;
    if (e < N_EDGES) {
        int pos = atomicAdd(&cursor[to_idx[e]], 1);
        inv[e] = pos;
    }
}

// ---------------------------------------------------------------------------
// Phase A: 512 threads / 8 waves per 64-edge tile. K split in two 192-col
// halves sharing one 24KB LDS tile. Wave w = (wr=w>>2, wc=w&3) computes the
// 32-row x 32-paircol quadrant: acc[2][4] = 32 AGPRs/thread.
//
// Register budget lesson (r5-r7): unified VGPR+AGPR budget = 512/waves_per_EU;
// the rocprof VGPR_Count column shows only the arch-VGPR part (acc lives in
// AGPRs). acc[4][4] (64 AGPR) + frags needed >128 total -> spill -> GBs of
// scratch traffic. acc[2][4] (32 AGPR) + ~65 VGPR fits the 128 cap at
// __launch_bounds__(512,4) (2 blocks/CU, 50% occupancy).
// ---------------------------------------------------------------------------
__global__ __launch_bounds__(512, 4)
void edge_msg_kernel(const unsigned short* __restrict__ nodef_bf,
                     const float* __restrict__ edgef,
                     const int* __restrict__ from_idx,
                     const int* __restrict__ to_idx,
                     const int* __restrict__ inv,
                     const bf16_t* __restrict__ WtAB,
                     const float* __restrict__ b_msg,
                     const float* __restrict__ b_rev,
                     unsigned int* __restrict__ msgs_u) {
    __shared__ char lds_raw[64 * 384];   // [64 rows][192 cols] bf16, XOR-swizzled
    __shared__ int s_from[64], s_dst[64], s_inv[64];

    const int tid = threadIdx.x;
    const int eb = blockIdx.x * 64;

    if (tid < 64) {
        s_from[tid] = from_idx[eb + tid];
        s_dst[tid]  = to_idx[eb + tid];
        s_inv[tid]  = inv[eb + tid];
    }

    const int wv = tid >> 6;     // 0..7
    const int wr = wv >> 2;      // 0..1: row half (32 rows)
    const int wc = wv & 3;       // 0..3: 32-paircol group
    const int lane = tid & 63;
    const int lhi = lane >> 4;   // 0..3
    const int llo = lane & 15;   // 0..15

    f32x4 acc[2][4];
#pragma unroll
    for (int m = 0; m < 2; ++m)
#pragma unroll
        for (int n = 0; n < 4; ++n)
            acc[m][n] = (f32x4){0.f, 0.f, 0.f, 0.f};

    // B pointers: n=0,1 -> msg cols wc*32+16n ; n=2,3 -> rev cols (+128)
    const bf16_t* bptr[4];
#pragma unroll
    for (int n = 0; n < 4; ++n) {
        int colb = (n < 2) ? (wc * 32 + 16 * n) : (128 + wc * 32 + 16 * (n - 2));
        bptr[n] = WtAB + (size_t)(colb + llo) * 384 + lhi * 8;
    }

    __syncthreads();

    // ---- half 0 stage: 64 rows x 24 chunks (16B): q<16 from, else to[0:64]
#pragma unroll
    for (int j = 0; j < 3; ++j) {
        int linear = tid + 512 * j;
        int r = linear / 24;
        int q = linear - r * 24;
        const u32x4* src = (q < 16)
            ? reinterpret_cast<const u32x4*>(nodef_bf + (size_t)s_from[r] * 128) + q
            : reinterpret_cast<const u32x4*>(nodef_bf + (size_t)s_dst[r] * 128) + (q - 16);
        u32x4 v = *src;
        int byte = (r * 384 + q * 16) ^ ((r & 7) << 4);
        *reinterpret_cast<u32x4*>(lds_raw + byte) = v;
    }
    __syncthreads();

    // ---- MFMA half 0: global ksteps 0..5
#pragma unroll
    for (int k0 = 0; k0 < 6; ++k0) {
        bf16x8 a[2], b[4];
#pragma unroll
        for (int m = 0; m < 2; ++m) {
            int ra = wr * 32 + 16 * m + llo;
            int byte = (ra * 384 + k0 * 64 + lhi * 16) ^ ((ra & 7) << 4);
            a[m] = *reinterpret_cast<const bf16x8*>(lds_raw + byte);
        }
#pragma unroll
        for (int n = 0; n < 4; ++n)
            b[n] = *reinterpret_cast<const bf16x8*>(bptr[n] + k0 * 32);
#pragma unroll
        for (int m = 0; m < 2; ++m)
#pragma unroll
            for (int n = 0; n < 4; ++n)
                acc[m][n] = __builtin_amdgcn_mfma_f32_16x16x32_bf16(a[m], b[n], acc[m][n], 0, 0, 0);
    }
    __syncthreads();

    // ---- half 1 stage: qq<8 -> to[64:128], else edgef f32->bf16
#pragma unroll
    for (int j = 0; j < 3; ++j) {
        int linear = tid + 512 * j;
        int r = linear / 24;
        int qq = linear - r * 24;
        u32x4 w;
        if (qq < 8) {
            w = *(reinterpret_cast<const u32x4*>(nodef_bf + (size_t)s_dst[r] * 128) + 8 + qq);
        } else {
            int c = qq - 8;   // 0..15 -> source floats 8c..8c+7
            const f4* ep = reinterpret_cast<const f4*>(edgef + (size_t)(eb + r) * 128 + c * 8);
            f4 v0 = ep[0];
            f4 v1 = ep[1];
            union { bf16_t b[8]; u32x4 u; } pk;
            pk.b[0] = (bf16_t)v0[0]; pk.b[1] = (bf16_t)v0[1];
            pk.b[2] = (bf16_t)v0[2]; pk.b[3] = (bf16_t)v0[3];
            pk.b[4] = (bf16_t)v1[0]; pk.b[5] = (bf16_t)v1[1];
            pk.b[6] = (bf16_t)v1[2]; pk.b[7] = (bf16_t)v1[3];
            w = pk.u;
        }
        int byte = (r * 384 + qq * 16) ^ ((r & 7) << 4);
        *reinterpret_cast<u32x4*>(lds_raw + byte) = w;
    }
    __syncthreads();

    // ---- MFMA half 1: global ksteps 6..11
#pragma unroll
    for (int k0 = 0; k0 < 6; ++k0) {
        bf16x8 a[2], b[4];
#pragma unroll
        for (int m = 0; m < 2; ++m) {
            int ra = wr * 32 + 16 * m + llo;
            int byte = (ra * 384 + k0 * 64 + lhi * 16) ^ ((ra & 7) << 4);
            a[m] = *reinterpret_cast<const bf16x8*>(lds_raw + byte);
        }
#pragma unroll
        for (int n = 0; n < 4; ++n)
            b[n] = *reinterpret_cast<const bf16x8*>(bptr[n] + (6 + k0) * 32);
#pragma unroll
        for (int m = 0; m < 2; ++m)
#pragma unroll
            for (int n = 0; n < 4; ++n)
                acc[m][n] = __builtin_amdgcn_mfma_f32_16x16x32_bf16(a[m], b[n], acc[m][n], 0, 0, 0);
    }

    // ---- epilogue: relu-sum both nets, pack bf16 pair, store at inv row ----
    const int c0 = wc * 32 + llo;
    const float bm0 = b_msg[c0], br0 = b_rev[c0];
    const float bm1 = b_msg[c0 + 16], br1 = b_rev[c0 + 16];
#pragma unroll
    for (int m = 0; m < 2; ++m) {
        int rbase = wr * 32 + 16 * m + lhi * 4;
#pragma unroll
        for (int r = 0; r < 4; ++r) {
            float v0 = fmaxf(acc[m][0][r] + bm0, 0.f) + fmaxf(acc[m][2][r] + br0, 0.f);
            float v1 = fmaxf(acc[m][1][r] + bm1, 0.f) + fmaxf(acc[m][3][r] + br1, 0.f);
            union { bf16_t b[2]; unsigned int u; } pk;
            pk.b[0] = (bf16_t)v0;
            pk.b[1] = (bf16_t)v1;
            msgs_u[(size_t)s_inv[rbase + r] * 64 + wc * 16 + llo] = pk.u;
        }
    }
}

// ---------------------------------------------------------------------------
// Phase B: per block of 64 nodes:
//   f32 register segsum of each node's CONTIGUOUS msgs range (CSR),
//   -> bf16 LDS tile [64][128] (swizzled, stored-column order),
//   MFMA with pi-baked WtU, residual + relu, store out.
// ---------------------------------------------------------------------------
__global__ __launch_bounds__(256, 4)
void node_upd_kernel(const unsigned int* __restrict__ msgs_u,
                     const int* __restrict__ row_start,
                     const float* __restrict__ nodef,
                     const bf16_t* __restrict__ WtU,
                     const float* __restrict__ b_upd,
                     float* __restrict__ out) {
    __shared__ char lds_raw[64 * 256];  // [64][128] bf16, swizzled
    __shared__ int s_rs[65];

    const int tid = threadIdx.x;
    const int nb = blockIdx.x * 64;

    if (tid < 65) {
        int nid = nb + tid;
        s_rs[tid] = (nid <= N_NODES) ? row_start[nid] : N_EDGES;
    }
    __syncthreads();

    {
        const int r = tid >> 2;      // node row 0..63
        const int q = tid & 3;       // 32-column chunk
        float s[32];
#pragma unroll
        for (int i = 0; i < 32; ++i) s[i] = 0.f;
        const int rs = s_rs[r], re = s_rs[r + 1];
        for (int e = rs; e < re; ++e) {
            const u32x4* p = reinterpret_cast<const u32x4*>(msgs_u + (size_t)e * 64 + q * 16);
#pragma unroll
            for (int i = 0; i < 4; ++i) {
                u32x4 w = p[i];
                s[8*i+0] += __uint_as_float(w[0] << 16);
                s[8*i+1] += __uint_as_float(w[0] & 0xffff0000u);
                s[8*i+2] += __uint_as_float(w[1] << 16);
                s[8*i+3] += __uint_as_float(w[1] & 0xffff0000u);
                s[8*i+4] += __uint_as_float(w[2] << 16);
                s[8*i+5] += __uint_as_float(w[2] & 0xffff0000u);
                s[8*i+6] += __uint_as_float(w[3] << 16);
                s[8*i+7] += __uint_as_float(w[3] & 0xffff0000u);
            }
        }
        // bf16-pack into LDS (swizzled), stored-column order
#pragma unroll
        for (int i = 0; i < 4; ++i) {
            union { bf16_t b[8]; u32x4 u; } pk;
#pragma unroll
            for (int w = 0; w < 8; ++w) pk.b[w] = (bf16_t)s[8*i + w];
            int byte = (r * 256 + q * 64 + i * 16) ^ ((r & 7) << 4);
            *reinterpret_cast<u32x4*>(lds_raw + byte) = pk.u;
        }
    }
    __syncthreads();

    const int wv = tid >> 6;
    const int lane = tid & 63;
    const int lhi = lane >> 4;
    const int llo = lane & 15;

    f32x4 acc[4][2];
#pragma unroll
    for (int m = 0; m < 4; ++m)
#pragma unroll
        for (int n = 0; n < 2; ++n)
            acc[m][n] = (f32x4){0.f, 0.f, 0.f, 0.f};

#pragma unroll
    for (int k0 = 0; k0 < 4; ++k0) {
        bf16x8 a[4], b[2];
#pragma unroll
        for (int m = 0; m < 4; ++m) {
            int ra = 16 * m + llo;
            int byte = (ra * 256 + (k0 * 32 + lhi * 8) * 2) ^ ((ra & 7) << 4);
            a[m] = *reinterpret_cast<const bf16x8*>(lds_raw + byte);
        }
#pragma unroll
        for (int n = 0; n < 2; ++n) {
            int col = wv * 32 + 16 * n + llo;
            b[n] = *reinterpret_cast<const bf16x8*>(WtU + (size_t)col * 128 + k0 * 32 + lhi * 8);
        }
#pragma unroll
        for (int m = 0; m < 4; ++m)
#pragma unroll
            for (int n = 0; n < 2; ++n)
                acc[m][n] = __builtin_amdgcn_mfma_f32_16x16x32_bf16(a[m], b[n], acc[m][n], 0, 0, 0);
    }

#pragma unroll
    for (int m = 0; m < 4; ++m) {
        int rbase = 16 * m + lhi * 4;
#pragma unroll
        for (int r = 0; r < 4; ++r) {
            int i = nb + rbase + r;
            if (i < N_NODES) {
#pragma unroll
                for (int n = 0; n < 2; ++n) {
                    int c = wv * 32 + 16 * n + llo;
                    out[(size_t)i * 128 + c] =
                        nodef[(size_t)i * 128 + c]
                        + fmaxf(acc[m][n][r] + b_upd[c], 0.f);
                }
            }
        }
    }
}

// ---------------------------------------------------------------------------
extern "C" void kernel_launch(void* const* d_in, const int* in_sizes, int n_in,
                              void* d_out, int out_size, void* d_ws, size_t ws_size,
                              hipStream_t stream) {
    const float* nodef    = (const float*)d_in[0];
    const float* edgef    = (const float*)d_in[1];
    const int*   from_idx = (const int*)d_in[2];
    const int*   to_idx   = (const int*)d_in[3];
    const float* Wmsg     = (const float*)d_in[4];
    const float* bmsg     = (const float*)d_in[5];
    const float* Wrev     = (const float*)d_in[6];
    const float* brev     = (const float*)d_in[7];
    const float* Wupd     = (const float*)d_in[8];
    const float* bupd     = (const float*)d_in[9];
    float* out = (float*)d_out;

    char* ws = (char*)d_ws;
    unsigned int*   msgs_u   = (unsigned int*)ws;              // 163,840,000 B
    bf16_t*         WtAB     = (bf16_t*)(ws + 163840000);      // 196,608 B
    bf16_t*         WtU      = (bf16_t*)(ws + 164036608);      // 32,768 B
    unsigned short* nodef_bf = (unsigned short*)(ws + 164069376); // 25,600,000 B
    int*            hist     = (int*)(ws + 189669376);         // 400,000 B
    int*            cursor   = (int*)(ws + 190069376);         // 400,000 B
    int*            rowstart = (int*)(ws + 190469376);         // 400,016 B
    int*            inv      = (int*)(ws + 190869392);         // 2,560,000 B
    int*            bsum     = (int*)(ws + 193429392);         // 400 B
    int*            bbase    = (int*)(ws + 193429792);         // 400 B
                                                               // total ~193.4 MB

    hipMemsetAsync(hist, 0, (size_t)N_NODES * sizeof(int), stream);

    convert_nodef_kernel<<<12500, 256, 0, stream>>>(nodef, nodef_bf);
    prep_weights_kernel<<<384, 256, 0, stream>>>(Wmsg, Wrev, Wupd, WtAB, WtU);
    hist_kernel<<<(N_EDGES + 255) / 256, 256, 0, stream>>>(to_idx, hist);
    scan_reduce_kernel<<<100, 1024, 0, stream>>>(hist, bsum);
    scan_base_kernel<<<1, 128, 0, stream>>>(bsum, bbase);
    scan_final_kernel<<<100, 1024, 0, stream>>>(hist, bbase, cursor, rowstart);
    inv_scatter_kernel<<<(N_EDGES + 255) / 256, 256, 0, stream>>>(to_idx, cursor, inv);
    edge_msg_kernel<<<N_EDGES / 64, 512, 0, stream>>>(
        nodef_bf, edgef, from_idx, to_idx, inv, WtAB, bmsg, brev, msgs_u);
    node_upd_kernel<<<(N_NODES + 63) / 64, 256, 0, stream>>>(
        msgs_u, rowstart, nodef, WtU, bupd, out);
}

// Round 9
// 461.916 us; speedup vs baseline: 1.4967x; 1.4967x over previous
//
#include <hip/hip_runtime.h>
#include <hip/hip_bf16.h>

#define N_NODES 100000
#define N_EDGES 640000

typedef __bf16 bf16_t;
typedef __bf16 bf16x8 __attribute__((ext_vector_type(8)));
typedef float f32x4 __attribute__((ext_vector_type(4)));
typedef float f4 __attribute__((ext_vector_type(4)));
typedef unsigned int u32x4 __attribute__((ext_vector_type(4)));

__device__ __forceinline__ float bflo(unsigned int u) { return __uint_as_float(u << 16); }
__device__ __forceinline__ float bfhi(unsigned int u) { return __uint_as_float(u & 0xffff0000u); }
__device__ __forceinline__ unsigned int bfpack(float a, float b) {
    union { bf16_t h[2]; unsigned int u; } pk;
    pk.h[0] = (bf16_t)a; pk.h[1] = (bf16_t)b;
    return pk.u;
}

// ===========================================================================
// Shared: CSR build (hist -> hierarchical scan -> inverse permutation)
// ===========================================================================
__global__ void hist_kernel(const int* __restrict__ to_idx, int* __restrict__ hist) {
    int e = blockIdx.x * 256 + threadIdx.x;
    if (e < N_EDGES) atomicAdd(&hist[to_idx[e]], 1);
}

#define SCAN_CH 1000  // N_NODES = 100 blocks x 1000

__global__ __launch_bounds__(1024)
void scan_reduce_kernel(const int* __restrict__ hist, int* __restrict__ bsum) {
    __shared__ int red[1024];
    int b = blockIdx.x, t = threadIdx.x;
    int v = (t < SCAN_CH) ? hist[b * SCAN_CH + t] : 0;
    red[t] = v;
    __syncthreads();
    for (int off = 512; off > 0; off >>= 1) {
        if (t < off) red[t] += red[t + off];
        __syncthreads();
    }
    if (t == 0) bsum[b] = red[0];
}

__global__ __launch_bounds__(128)
void scan_base_kernel(const int* __restrict__ bsum, int* __restrict__ bbase) {
    __shared__ int s[128];
    int t = threadIdx.x;
    int v = (t < 100) ? bsum[t] : 0;
    s[t] = v;
    __syncthreads();
    for (int off = 1; off < 128; off <<= 1) {
        int u = (t >= off) ? s[t - off] : 0;
        __syncthreads();
        s[t] += u;
        __syncthreads();
    }
    if (t < 100) bbase[t] = s[t] - v;
}

__global__ __launch_bounds__(1024)
void scan_final_kernel(const int* __restrict__ hist,
                       const int* __restrict__ bbase,
                       int* __restrict__ cursor,
                       int* __restrict__ row_start) {
    __shared__ int s[1024];
    int b = blockIdx.x, t = threadIdx.x;
    int v = (t < SCAN_CH) ? hist[b * SCAN_CH + t] : 0;
    s[t] = v;
    __syncthreads();
    for (int off = 1; off < 1024; off <<= 1) {
        int u = (t >= off) ? s[t - off] : 0;
        __syncthreads();
        s[t] += u;
        __syncthreads();
    }
    int excl = bbase[b] + s[t] - v;
    if (t < SCAN_CH) {
        cursor[b * SCAN_CH + t] = excl;
        row_start[b * SCAN_CH + t] = excl;
    }
    if (b == 99 && t == SCAN_CH - 1) row_start[N_NODES] = excl + v;
}

__global__ void inv_scatter_kernel(const int* __restrict__ to_idx,
                                   int* __restrict__ cursor,
                                   int* __restrict__ inv) {
    int e = blockIdx.x * 256 + threadIdx.x;
    if (e < N_EDGES) {
        int pos = atomicAdd(&cursor[to_idx[e]], 1);
        inv[e] = pos;
    }
}

// ===========================================================================
// NEW PATH: factored GEMM.
//   A[100K][256 u32] bf16 pair-packed: [msgF 64u32 | revF 64 | msgT 64 | revT 64]
//   Wt1 [512][128]: rows 0-127 msgF cols (W_msg k=0..127), 128-255 revF,
//                   256-383 msgT (W_msg k=128..255), 384-511 revT.
//   WtE [256][128]: rows 0-127 msgE cols (W_msg k=256..383), 128-255 revE.
//   WtU [128][128]: pi-baked for pair-packed msgs (same as old path).
// ===========================================================================
__global__ void prep_w_new(const float* __restrict__ Wmsg,
                           const float* __restrict__ Wrev,
                           const float* __restrict__ Wupd,
                           bf16_t* __restrict__ Wt1,
                           bf16_t* __restrict__ WtE,
                           bf16_t* __restrict__ WtU) {
    int idx = blockIdx.x * 256 + threadIdx.x;
    if (idx < 512 * 128) {
        int p = idx >> 7, k = idx & 127;
        int blk = p >> 7, c = p & 127;
        float v;
        if (blk == 0)      v = Wmsg[k * 128 + c];
        else if (blk == 1) v = Wrev[k * 128 + c];
        else if (blk == 2) v = Wmsg[(128 + k) * 128 + c];
        else               v = Wrev[(128 + k) * 128 + c];
        Wt1[idx] = (bf16_t)v;
    }
    if (idx < 256 * 128) {
        int p = idx >> 7, k = idx & 127;
        float v = (p < 128) ? Wmsg[(256 + k) * 128 + p]
                            : Wrev[(256 + k) * 128 + (p - 128)];
        WtE[idx] = (bf16_t)v;
    }
    if (idx < 128 * 128) {
        int n = idx >> 7, p = idx & 127;
        int colp = 32 * (p >> 5) + ((p >> 1) & 15) + 16 * (p & 1);
        WtU[idx] = (bf16_t)Wupd[colp * 128 + n];
    }
}

// ---------------------------------------------------------------------------
// P1: A = node @ Wt1-half. Pure streaming GEMM, 64 nodes x 256 cols per block,
// blockIdx.y selects F-half (0) or T-half (1).
// ---------------------------------------------------------------------------
__global__ __launch_bounds__(512, 4)
void proj_node_kernel(const float* __restrict__ nodef,
                      const bf16_t* __restrict__ Wt1,
                      unsigned int* __restrict__ A_u) {
    __shared__ char lds_raw[64 * 256];  // [64][128] bf16, swizzled
    const int tid = threadIdx.x;
    const int nb = blockIdx.x * 64;
    const int by = blockIdx.y;  // 0=F, 1=T

    // stage: 64 rows x 32 float4 = 2048 / 512thr = 4 iters
#pragma unroll
    for (int j = 0; j < 4; ++j) {
        int linear = tid + 512 * j;
        int r = linear >> 5, q = linear & 31;
        int node = nb + r;
        f4 v = (f4){0.f, 0.f, 0.f, 0.f};
        if (node < N_NODES)
            v = *reinterpret_cast<const f4*>(nodef + (size_t)node * 128 + q * 4);
        union { bf16_t b[4]; uint2 u; } pk;
        pk.b[0] = (bf16_t)v[0]; pk.b[1] = (bf16_t)v[1];
        pk.b[2] = (bf16_t)v[2]; pk.b[3] = (bf16_t)v[3];
        int byte = (r * 256 + q * 8) ^ ((r & 7) << 4);
        *reinterpret_cast<uint2*>(lds_raw + byte) = pk.u;
    }
    __syncthreads();

    const int wv = tid >> 6;
    const int wr = wv >> 2, wc = wv & 3;
    const int lane = tid & 63;
    const int lhi = lane >> 4, llo = lane & 15;

    f32x4 acc[2][4];
#pragma unroll
    for (int m = 0; m < 2; ++m)
#pragma unroll
        for (int n = 0; n < 4; ++n)
            acc[m][n] = (f32x4){0.f, 0.f, 0.f, 0.f};

    const bf16_t* bptr[4];
#pragma unroll
    for (int n = 0; n < 4; ++n) {
        int colb = (n < 2) ? (wc * 32 + 16 * n) : (128 + wc * 32 + 16 * (n - 2));
        bptr[n] = Wt1 + (size_t)(by * 256 + colb + llo) * 128 + lhi * 8;
    }

#pragma unroll
    for (int k0 = 0; k0 < 4; ++k0) {
        bf16x8 a[2], b[4];
#pragma unroll
        for (int m = 0; m < 2; ++m) {
            int ra = wr * 32 + 16 * m + llo;
            int byte = (ra * 256 + (k0 * 32 + lhi * 8) * 2) ^ ((ra & 7) << 4);
            a[m] = *reinterpret_cast<const bf16x8*>(lds_raw + byte);
        }
#pragma unroll
        for (int n = 0; n < 4; ++n)
            b[n] = *reinterpret_cast<const bf16x8*>(bptr[n] + k0 * 32);
#pragma unroll
        for (int m = 0; m < 2; ++m)
#pragma unroll
            for (int n = 0; n < 4; ++n)
                acc[m][n] = __builtin_amdgcn_mfma_f32_16x16x32_bf16(a[m], b[n], acc[m][n], 0, 0, 0);
    }

    // store pair-packed: msg pair and rev pair, no bias, no relu
    const int wli = wc * 16 + llo;
#pragma unroll
    for (int m = 0; m < 2; ++m) {
        int rbase = wr * 32 + 16 * m + lhi * 4;
#pragma unroll
        for (int r = 0; r < 4; ++r) {
            int node = nb + rbase + r;
            if (node < N_NODES) {
                size_t base = (size_t)node * 256 + by * 128;
                A_u[base + wli]      = bfpack(acc[m][0][r], acc[m][1][r]);
                A_u[base + 64 + wli] = bfpack(acc[m][2][r], acc[m][3][r]);
            }
        }
    }
}

// ---------------------------------------------------------------------------
// edge_fused: per 32-edge block (256thr, 4 waves):
//   streaming stage edgef -> LDS (no index dependence!), MFMA K=128 (E-part),
//   then BARRIER-FREE epilogue: issue all 32 A-gathers per thread, one wait,
//   msg = relu(E+bm+msgF+msgT) + relu(...rev...), store packed at inv[e].
// ---------------------------------------------------------------------------
__global__ __launch_bounds__(256, 4)
void edge_fused_kernel(const float* __restrict__ edgef,
                       const int* __restrict__ from_idx,
                       const int* __restrict__ to_idx,
                       const int* __restrict__ inv,
                       const unsigned int* __restrict__ A_u,
                       const bf16_t* __restrict__ WtE,
                       const float* __restrict__ b_msg,
                       const float* __restrict__ b_rev,
                       unsigned int* __restrict__ msgs_u) {
    __shared__ char lds_raw[32 * 256];  // [32][128] bf16, swizzled
    __shared__ int s_from[32], s_dst[32], s_inv[32];

    const int tid = threadIdx.x;
    const int eb = blockIdx.x * 32;

    if (tid < 32) {
        s_from[tid] = from_idx[eb + tid];
        s_dst[tid]  = to_idx[eb + tid];
        s_inv[tid]  = inv[eb + tid];
    }

    // stage: 32 rows x 32 float4 = 1024 / 256thr = 4 iters (pure streaming)
#pragma unroll
    for (int j = 0; j < 4; ++j) {
        int linear = tid + 256 * j;
        int r = linear >> 5, q = linear & 31;
        f4 v = *reinterpret_cast<const f4*>(edgef + (size_t)(eb + r) * 128 + q * 4);
        union { bf16_t b[4]; uint2 u; } pk;
        pk.b[0] = (bf16_t)v[0]; pk.b[1] = (bf16_t)v[1];
        pk.b[2] = (bf16_t)v[2]; pk.b[3] = (bf16_t)v[3];
        int byte = (r * 256 + q * 8) ^ ((r & 7) << 4);
        *reinterpret_cast<uint2*>(lds_raw + byte) = pk.u;
    }
    __syncthreads();

    const int wc = tid >> 6;       // 4 waves = 4 paircol groups
    const int lane = tid & 63;
    const int lhi = lane >> 4, llo = lane & 15;

    f32x4 acc[2][4];
#pragma unroll
    for (int m = 0; m < 2; ++m)
#pragma unroll
        for (int n = 0; n < 4; ++n)
            acc[m][n] = (f32x4){0.f, 0.f, 0.f, 0.f};

    const bf16_t* bptr[4];
#pragma unroll
    for (int n = 0; n < 4; ++n) {
        int colb = (n < 2) ? (wc * 32 + 16 * n) : (128 + wc * 32 + 16 * (n - 2));
        bptr[n] = WtE + (size_t)(colb + llo) * 128 + lhi * 8;
    }

#pragma unroll
    for (int k0 = 0; k0 < 4; ++k0) {
        bf16x8 a[2], b[4];
#pragma unroll
        for (int m = 0; m < 2; ++m) {
            int ra = 16 * m + llo;
            int byte = (ra * 256 + (k0 * 32 + lhi * 8) * 2) ^ ((ra & 7) << 4);
            a[m] = *reinterpret_cast<const bf16x8*>(lds_raw + byte);
        }
#pragma unroll
        for (int n = 0; n < 4; ++n)
            b[n] = *reinterpret_cast<const bf16x8*>(bptr[n] + k0 * 32);
#pragma unroll
        for (int m = 0; m < 2; ++m)
#pragma unroll
            for (int n = 0; n < 4; ++n)
                acc[m][n] = __builtin_amdgcn_mfma_f32_16x16x32_bf16(a[m], b[n], acc[m][n], 0, 0, 0);
    }

    // ---- barrier-free gather phase: issue all 32 loads, then combine ----
    const int wli = wc * 16 + llo;
    unsigned int g[2][4][4];  // [m][r][msgF, revF, msgT, revT]
#pragma unroll
    for (int m = 0; m < 2; ++m) {
#pragma unroll
        for (int r = 0; r < 4; ++r) {
            int rr = 16 * m + lhi * 4 + r;
            const unsigned int* af = A_u + (size_t)s_from[rr] * 256;
            const unsigned int* at = A_u + (size_t)s_dst[rr] * 256 + 128;
            g[m][r][0] = af[wli];
            g[m][r][1] = af[64 + wli];
            g[m][r][2] = at[wli];
            g[m][r][3] = at[64 + wli];
        }
    }

    const int c0 = wc * 32 + llo;
    const float bm0 = b_msg[c0], bm1 = b_msg[c0 + 16];
    const float br0 = b_rev[c0], br1 = b_rev[c0 + 16];
#pragma unroll
    for (int m = 0; m < 2; ++m) {
#pragma unroll
        for (int r = 0; r < 4; ++r) {
            int rr = 16 * m + lhi * 4 + r;
            float m0 = fmaxf(acc[m][0][r] + bm0 + bflo(g[m][r][0]) + bflo(g[m][r][2]), 0.f);
            float m1 = fmaxf(acc[m][1][r] + bm1 + bfhi(g[m][r][0]) + bfhi(g[m][r][2]), 0.f);
            float r0 = fmaxf(acc[m][2][r] + br0 + bflo(g[m][r][1]) + bflo(g[m][r][3]), 0.f);
            float r1 = fmaxf(acc[m][3][r] + br1 + bfhi(g[m][r][1]) + bfhi(g[m][r][3]), 0.f);
            msgs_u[(size_t)s_inv[rr] * 64 + wli] = bfpack(m0 + r0, m1 + r1);
        }
    }
}

// ===========================================================================
// Shared P4: node update (CSR segsum of packed msgs -> MFMA w/ pi-baked WtU)
// ===========================================================================
__global__ __launch_bounds__(256, 4)
void node_upd_kernel(const unsigned int* __restrict__ msgs_u,
                     const int* __restrict__ row_start,
                     const float* __restrict__ nodef,
                     const bf16_t* __restrict__ WtU,
                     const float* __restrict__ b_upd,
                     float* __restrict__ out) {
    __shared__ char lds_raw[64 * 256];
    __shared__ int s_rs[65];

    const int tid = threadIdx.x;
    const int nb = blockIdx.x * 64;

    if (tid < 65) {
        int nid = nb + tid;
        s_rs[tid] = (nid <= N_NODES) ? row_start[nid] : N_EDGES;
    }
    __syncthreads();

    {
        const int r = tid >> 2;
        const int q = tid & 3;
        float s[32];
#pragma unroll
        for (int i = 0; i < 32; ++i) s[i] = 0.f;
        const int rs = s_rs[r], re = s_rs[r + 1];
        for (int e = rs; e < re; ++e) {
            const u32x4* p = reinterpret_cast<const u32x4*>(msgs_u + (size_t)e * 64 + q * 16);
#pragma unroll
            for (int i = 0; i < 4; ++i) {
                u32x4 w = p[i];
                s[8*i+0] += bflo(w[0]); s[8*i+1] += bfhi(w[0]);
                s[8*i+2] += bflo(w[1]); s[8*i+3] += bfhi(w[1]);
                s[8*i+4] += bflo(w[2]); s[8*i+5] += bfhi(w[2]);
                s[8*i+6] += bflo(w[3]); s[8*i+7] += bfhi(w[3]);
            }
        }
#pragma unroll
        for (int i = 0; i < 4; ++i) {
            union { bf16_t b[8]; u32x4 u; } pk;
#pragma unroll
            for (int w = 0; w < 8; ++w) pk.b[w] = (bf16_t)s[8*i + w];
            int byte = (r * 256 + q * 64 + i * 16) ^ ((r & 7) << 4);
            *reinterpret_cast<u32x4*>(lds_raw + byte) = pk.u;
        }
    }
    __syncthreads();

    const int wv = tid >> 6;
    const int lane = tid & 63;
    const int lhi = lane >> 4, llo = lane & 15;

    f32x4 acc[4][2];
#pragma unroll
    for (int m = 0; m < 4; ++m)
#pragma unroll
        for (int n = 0; n < 2; ++n)
            acc[m][n] = (f32x4){0.f, 0.f, 0.f, 0.f};

#pragma unroll
    for (int k0 = 0; k0 < 4; ++k0) {
        bf16x8 a[4], b[2];
#pragma unroll
        for (int m = 0; m < 4; ++m) {
            int ra = 16 * m + llo;
            int byte = (ra * 256 + (k0 * 32 + lhi * 8) * 2) ^ ((ra & 7) << 4);
            a[m] = *reinterpret_cast<const bf16x8*>(lds_raw + byte);
        }
#pragma unroll
        for (int n = 0; n < 2; ++n) {
            int col = wv * 32 + 16 * n + llo;
            b[n] = *reinterpret_cast<const bf16x8*>(WtU + (size_t)col * 128 + k0 * 32 + lhi * 8);
        }
#pragma unroll
        for (int m = 0; m < 4; ++m)
#pragma unroll
            for (int n = 0; n < 2; ++n)
                acc[m][n] = __builtin_amdgcn_mfma_f32_16x16x32_bf16(a[m], b[n], acc[m][n], 0, 0, 0);
    }

#pragma unroll
    for (int m = 0; m < 4; ++m) {
        int rbase = 16 * m + lhi * 4;
#pragma unroll
        for (int r = 0; r < 4; ++r) {
            int i = nb + rbase + r;
            if (i < N_NODES) {
#pragma unroll
                for (int n = 0; n < 2; ++n) {
                    int c = wv * 32 + 16 * n + llo;
                    out[(size_t)i * 128 + c] =
                        nodef[(size_t)i * 128 + c]
                        + fmaxf(acc[m][n][r] + b_upd[c], 0.f);
                }
            }
        }
    }
}

// ===========================================================================
// OLD PATH (r8 fallback, used only if ws_size too small for the new path)
// ===========================================================================
__global__ __launch_bounds__(256)
void convert_nodef_kernel(const float* __restrict__ nodef,
                          unsigned short* __restrict__ nodef_bf) {
    int i = blockIdx.x * 256 + threadIdx.x;
    if (i < N_NODES * 32) {
        f4 v = *reinterpret_cast<const f4*>(nodef + (size_t)i * 4);
        union { bf16_t b[4]; unsigned long long ll; } pk;
        pk.b[0] = (bf16_t)v[0]; pk.b[1] = (bf16_t)v[1];
        pk.b[2] = (bf16_t)v[2]; pk.b[3] = (bf16_t)v[3];
        *reinterpret_cast<unsigned long long*>(nodef_bf + (size_t)i * 4) = pk.ll;
    }
}

__global__ void prep_w_old(const float* __restrict__ Wmsg,
                           const float* __restrict__ Wrev,
                           const float* __restrict__ Wupd,
                           bf16_t* __restrict__ WtAB,
                           bf16_t* __restrict__ WtU) {
    int idx = blockIdx.x * 256 + threadIdx.x;
    if (idx < 256 * 384) {
        int n = idx / 384;
        int k = idx - n * 384;
        float v = (n < 128) ? Wmsg[k * 128 + n] : Wrev[k * 128 + (n - 128)];
        WtAB[idx] = (bf16_t)v;
    }
    if (idx < 128 * 128) {
        int n = idx >> 7, p = idx & 127;
        int colp = 32 * (p >> 5) + ((p >> 1) & 15) + 16 * (p & 1);
        WtU[idx] = (bf16_t)Wupd[colp * 128 + n];
    }
}

__global__ __launch_bounds__(512, 4)
void edge_msg_old_kernel(const unsigned short* __restrict__ nodef_bf,
                         const float* __restrict__ edgef,
                         const int* __restrict__ from_idx,
                         const int* __restrict__ to_idx,
                         const int* __restrict__ inv,
                         const bf16_t* __restrict__ WtAB,
                         const float* __restrict__ b_msg,
                         const float* __restrict__ b_rev,
                         unsigned int* __restrict__ msgs_u) {
    __shared__ char lds_raw[64 * 384];
    __shared__ int s_from[64], s_dst[64], s_inv[64];

    const int tid = threadIdx.x;
    const int eb = blockIdx.x * 64;

    if (tid < 64) {
        s_from[tid] = from_idx[eb + tid];
        s_dst[tid]  = to_idx[eb + tid];
        s_inv[tid]  = inv[eb + tid];
    }

    const int wv = tid >> 6;
    const int wr = wv >> 2, wc = wv & 3;
    const int lane = tid & 63;
    const int lhi = lane >> 4, llo = lane & 15;

    f32x4 acc[2][4];
#pragma unroll
    for (int m = 0; m < 2; ++m)
#pragma unroll
        for (int n = 0; n < 4; ++n)
            acc[m][n] = (f32x4){0.f, 0.f, 0.f, 0.f};

    const bf16_t* bptr[4];
#pragma unroll
    for (int n = 0; n < 4; ++n) {
        int colb = (n < 2) ? (wc * 32 + 16 * n) : (128 + wc * 32 + 16 * (n - 2));
        bptr[n] = WtAB + (size_t)(colb + llo) * 384 + lhi * 8;
    }

    __syncthreads();

#pragma unroll
    for (int j = 0; j < 3; ++j) {
        int linear = tid + 512 * j;
        int r = linear / 24;
        int q = linear - r * 24;
        const u32x4* src = (q < 16)
            ? reinterpret_cast<const u32x4*>(nodef_bf + (size_t)s_from[r] * 128) + q
            : reinterpret_cast<const u32x4*>(nodef_bf + (size_t)s_dst[r] * 128) + (q - 16);
        u32x4 v = *src;
        int byte = (r * 384 + q * 16) ^ ((r & 7) << 4);
        *reinterpret_cast<u32x4*>(lds_raw + byte) = v;
    }
    __syncthreads();

#pragma unroll
    for (int k0 = 0; k0 < 6; ++k0) {
        bf16x8 a[2], b[4];
#pragma unroll
        for (int m = 0; m < 2; ++m) {
            int ra = wr * 32 + 16 * m + llo;
            int byte = (ra * 384 + k0 * 64 + lhi * 16) ^ ((ra & 7) << 4);
            a[m] = *reinterpret_cast<const bf16x8*>(lds_raw + byte);
        }
#pragma unroll
        for (int n = 0; n < 4; ++n)
            b[n] = *reinterpret_cast<const bf16x8*>(bptr[n] + k0 * 32);
#pragma unroll
        for (int m = 0; m < 2; ++m)
#pragma unroll
            for (int n = 0; n < 4; ++n)
                acc[m][n] = __builtin_amdgcn_mfma_f32_16x16x32_bf16(a[m], b[n], acc[m][n], 0, 0, 0);
    }
    __syncthreads();

#pragma unroll
    for (int j = 0; j < 3; ++j) {
        int linear = tid + 512 * j;
        int r = linear / 24;
        int qq = linear - r * 24;
        u32x4 w;
        if (qq < 8) {
            w = *(reinterpret_cast<const u32x4*>(nodef_bf + (size_t)s_dst[r] * 128) + 8 + qq);
        } else {
            int c = qq - 8;
            const f4* ep = reinterpret_cast<const f4*>(edgef + (size_t)(eb + r) * 128 + c * 8);
            f4 v0 = ep[0];
            f4 v1 = ep[1];
            union { bf16_t b[8]; u32x4 u; } pk;
            pk.b[0] = (bf16_t)v0[0]; pk.b[1] = (bf16_t)v0[1];
            pk.b[2] = (bf16_t)v0[2]; pk.b[3] = (bf16_t)v0[3];
            pk.b[4] = (bf16_t)v1[0]; pk.b[5] = (bf16_t)v1[1];
            pk.b[6] = (bf16_t)v1[2]; pk.b[7] = (bf16_t)v1[3];
            w = pk.u;
        }
        int byte = (r * 384 + qq * 16) ^ ((r & 7) << 4);
        *reinterpret_cast<u32x4*>(lds_raw + byte) = w;
    }
    __syncthreads();

#pragma unroll
    for (int k0 = 0; k0 < 6; ++k0) {
        bf16x8 a[2], b[4];
#pragma unroll
        for (int m = 0; m < 2; ++m) {
            int ra = wr * 32 + 16 * m + llo;
            int byte = (ra * 384 + k0 * 64 + lhi * 16) ^ ((ra & 7) << 4);
            a[m] = *reinterpret_cast<const bf16x8*>(lds_raw + byte);
        }
#pragma unroll
        for (int n = 0; n < 4; ++n)
            b[n] = *reinterpret_cast<const bf16x8*>(bptr[n] + (6 + k0) * 32);
#pragma unroll
        for (int m = 0; m < 2; ++m)
#pragma unroll
            for (int n = 0; n < 4; ++n)
                acc[m][n] = __builtin_amdgcn_mfma_f32_16x16x32_bf16(a[m], b[n], acc[m][n], 0, 0, 0);
    }

    const int c0 = wc * 32 + llo;
    const float bm0 = b_msg[c0], br0 = b_rev[c0];
    const float bm1 = b_msg[c0 + 16], br1 = b_rev[c0 + 16];
#pragma unroll
    for (int m = 0; m < 2; ++m) {
        int rbase = wr * 32 + 16 * m + lhi * 4;
#pragma unroll
        for (int r = 0; r < 4; ++r) {
            float v0 = fmaxf(acc[m][0][r] + bm0, 0.f) + fmaxf(acc[m][2][r] + br0, 0.f);
            float v1 = fmaxf(acc[m][1][r] + bm1, 0.f) + fmaxf(acc[m][3][r] + br1, 0.f);
            msgs_u[(size_t)s_inv[rbase + r] * 64 + wc * 16 + llo] = bfpack(v0, v1);
        }
    }
}

// ===========================================================================
extern "C" void kernel_launch(void* const* d_in, const int* in_sizes, int n_in,
                              void* d_out, int out_size, void* d_ws, size_t ws_size,
                              hipStream_t stream) {
    const float* nodef    = (const float*)d_in[0];
    const float* edgef    = (const float*)d_in[1];
    const int*   from_idx = (const int*)d_in[2];
    const int*   to_idx   = (const int*)d_in[3];
    const float* Wmsg     = (const float*)d_in[4];
    const float* bmsg     = (const float*)d_in[5];
    const float* Wrev     = (const float*)d_in[6];
    const float* brev     = (const float*)d_in[7];
    const float* Wupd     = (const float*)d_in[8];
    const float* bupd     = (const float*)d_in[9];
    float* out = (float*)d_out;
    char* ws = (char*)d_ws;

    if (ws_size >= 271000000) {
        // ---------------- NEW PATH: factored GEMM ----------------
        unsigned int* A_u      = (unsigned int*)ws;               // 102,400,000
        unsigned int* msgs_u   = (unsigned int*)(ws + 102400000); // 163,840,000
        bf16_t*       Wt1      = (bf16_t*)(ws + 266240000);       // 131,072
        bf16_t*       WtE      = (bf16_t*)(ws + 266371072);       // 65,536
        bf16_t*       WtU      = (bf16_t*)(ws + 266436608);       // 32,768
        int*          hist     = (int*)(ws + 266469376);          // 400,000
        int*          cursor   = (int*)(ws + 266869376);          // 400,000
        int*          rowstart = (int*)(ws + 267269376);          // 400,016
        int*          inv      = (int*)(ws + 267669392);          // 2,560,000
        int*          bsum     = (int*)(ws + 270229392);          // 400
        int*          bbase    = (int*)(ws + 270229792);          // 400

        hipMemsetAsync(hist, 0, (size_t)N_NODES * sizeof(int), stream);
        prep_w_new<<<256, 256, 0, stream>>>(Wmsg, Wrev, Wupd, Wt1, WtE, WtU);
        hist_kernel<<<(N_EDGES + 255) / 256, 256, 0, stream>>>(to_idx, hist);
        scan_reduce_kernel<<<100, 1024, 0, stream>>>(hist, bsum);
        scan_base_kernel<<<1, 128, 0, stream>>>(bsum, bbase);
        scan_final_kernel<<<100, 1024, 0, stream>>>(hist, bbase, cursor, rowstart);
        inv_scatter_kernel<<<(N_EDGES + 255) / 256, 256, 0, stream>>>(to_idx, cursor, inv);
        proj_node_kernel<<<dim3((N_NODES + 63) / 64, 2), 512, 0, stream>>>(nodef, Wt1, A_u);
        edge_fused_kernel<<<N_EDGES / 32, 256, 0, stream>>>(
            edgef, from_idx, to_idx, inv, A_u, WtE, bmsg, brev, msgs_u);
        node_upd_kernel<<<(N_NODES + 63) / 64, 256, 0, stream>>>(
            msgs_u, rowstart, nodef, WtU, bupd, out);
    } else {
        // ---------------- OLD PATH (r8) ----------------
        unsigned int*   msgs_u   = (unsigned int*)ws;                 // 163,840,000
        bf16_t*         WtAB     = (bf16_t*)(ws + 163840000);         // 196,608
        bf16_t*         WtU      = (bf16_t*)(ws + 164036608);         // 32,768
        unsigned short* nodef_bf = (unsigned short*)(ws + 164069376); // 25,600,000
        int*            hist     = (int*)(ws + 189669376);            // 400,000
        int*            cursor   = (int*)(ws + 190069376);            // 400,000
        int*            rowstart = (int*)(ws + 190469376);            // 400,016
        int*            inv      = (int*)(ws + 190869392);            // 2,560,000
        int*            bsum     = (int*)(ws + 193429392);            // 400
        int*            bbase    = (int*)(ws + 193429792);            // 400

        hipMemsetAsync(hist, 0, (size_t)N_NODES * sizeof(int), stream);
        convert_nodef_kernel<<<12500, 256, 0, stream>>>(nodef, nodef_bf);
        prep_w_old<<<384, 256, 0, stream>>>(Wmsg, Wrev, Wupd, WtAB, WtU);
        hist_kernel<<<(N_EDGES + 255) / 256, 256, 0, stream>>>(to_idx, hist);
        scan_reduce_kernel<<<100, 1024, 0, stream>>>(hist, bsum);
        scan_base_kernel<<<1, 128, 0, stream>>>(bsum, bbase);
        scan_final_kernel<<<100, 1024, 0, stream>>>(hist, bbase, cursor, rowstart);
        inv_scatter_kernel<<<(N_EDGES + 255) / 256, 256, 0, stream>>>(to_idx, cursor, inv);
        edge_msg_old_kernel<<<N_EDGES / 64, 512, 0, stream>>>(
            nodef_bf, edgef, from_idx, to_idx, inv, WtAB, bmsg, brev, msgs_u);
        node_upd_kernel<<<(N_NODES + 63) / 64, 256, 0, stream>>>(
            msgs_u, rowstart, nodef, WtU, bupd, out);
    }
}

// Round 10
// 457.756 us; speedup vs baseline: 1.5103x; 1.0091x over previous
//
#include <hip/hip_runtime.h>
#include <hip/hip_bf16.h>

#define N_NODES 100000
#define N_EDGES 640000

typedef __bf16 bf16_t;
typedef __bf16 bf16x8 __attribute__((ext_vector_type(8)));
typedef float f32x4 __attribute__((ext_vector_type(4)));
typedef float f4 __attribute__((ext_vector_type(4)));
typedef unsigned int u32x4 __attribute__((ext_vector_type(4)));

__device__ __forceinline__ float bflo(unsigned int u) { return __uint_as_float(u << 16); }
__device__ __forceinline__ float bfhi(unsigned int u) { return __uint_as_float(u & 0xffff0000u); }
__device__ __forceinline__ unsigned int bfpack(float a, float b) {
    union { bf16_t h[2]; unsigned int u; } pk;
    pk.h[0] = (bf16_t)a; pk.h[1] = (bf16_t)b;
    return pk.u;
}

// ===========================================================================
// CSR build (hist -> hierarchical scan -> inverse permutation)
// ===========================================================================
__global__ void hist_kernel(const int* __restrict__ to_idx, int* __restrict__ hist) {
    int e = blockIdx.x * 256 + threadIdx.x;
    if (e < N_EDGES) atomicAdd(&hist[to_idx[e]], 1);
}

#define SCAN_CH 1000  // N_NODES = 100 blocks x 1000

__global__ __launch_bounds__(1024)
void scan_reduce_kernel(const int* __restrict__ hist, int* __restrict__ bsum) {
    __shared__ int red[1024];
    int b = blockIdx.x, t = threadIdx.x;
    int v = (t < SCAN_CH) ? hist[b * SCAN_CH + t] : 0;
    red[t] = v;
    __syncthreads();
    for (int off = 512; off > 0; off >>= 1) {
        if (t < off) red[t] += red[t + off];
        __syncthreads();
    }
    if (t == 0) bsum[b] = red[0];
}

__global__ __launch_bounds__(128)
void scan_base_kernel(const int* __restrict__ bsum, int* __restrict__ bbase) {
    __shared__ int s[128];
    int t = threadIdx.x;
    int v = (t < 100) ? bsum[t] : 0;
    s[t] = v;
    __syncthreads();
    for (int off = 1; off < 128; off <<= 1) {
        int u = (t >= off) ? s[t - off] : 0;
        __syncthreads();
        s[t] += u;
        __syncthreads();
    }
    if (t < 100) bbase[t] = s[t] - v;
}

__global__ __launch_bounds__(1024)
void scan_final_kernel(const int* __restrict__ hist,
                       const int* __restrict__ bbase,
                       int* __restrict__ cursor,
                       int* __restrict__ row_start) {
    __shared__ int s[1024];
    int b = blockIdx.x, t = threadIdx.x;
    int v = (t < SCAN_CH) ? hist[b * SCAN_CH + t] : 0;
    s[t] = v;
    __syncthreads();
    for (int off = 1; off < 1024; off <<= 1) {
        int u = (t >= off) ? s[t - off] : 0;
        __syncthreads();
        s[t] += u;
        __syncthreads();
    }
    int excl = bbase[b] + s[t] - v;
    if (t < SCAN_CH) {
        cursor[b * SCAN_CH + t] = excl;
        row_start[b * SCAN_CH + t] = excl;
    }
    if (b == 99 && t == SCAN_CH - 1) row_start[N_NODES] = excl + v;
}

__global__ void inv_scatter_kernel(const int* __restrict__ to_idx,
                                   int* __restrict__ cursor,
                                   int* __restrict__ inv) {
    int e = blockIdx.x * 256 + threadIdx.x;
    if (e < N_EDGES) {
        int pos = atomicAdd(&cursor[to_idx[e]], 1);
        inv[e] = pos;
    }
}

// ===========================================================================
// Factored GEMM path.
//   A[100K][256 u32], INTERLEAVED pairs so each (edge,side) gather is ONE
//   uint2 covering a fully-used 128B line region:
//     F-half: u32[2*c]   = msg pair c (cols 2c,2c+1 of W_msg k=0..127 proj)
//             u32[2*c+1] = rev pair c
//     T-half (offset 128): same for k=128..255 projections.
//   Wt1 [512][128]: rows 0-127 msgF cols, 128-255 revF, 256-383 msgT, 384-511 revT
//   WtE [256][128]: rows 0-127 msgE, 128-255 revE (W k=256..383)
//   WtU [128][128]: pi-baked for pair-packed msgs.
// ===========================================================================
__global__ void prep_w_new(const float* __restrict__ Wmsg,
                           const float* __restrict__ Wrev,
                           const float* __restrict__ Wupd,
                           bf16_t* __restrict__ Wt1,
                           bf16_t* __restrict__ WtE,
                           bf16_t* __restrict__ WtU) {
    int idx = blockIdx.x * 256 + threadIdx.x;
    if (idx < 512 * 128) {
        int p = idx >> 7, k = idx & 127;
        int blk = p >> 7, c = p & 127;
        float v;
        if (blk == 0)      v = Wmsg[k * 128 + c];
        else if (blk == 1) v = Wrev[k * 128 + c];
        else if (blk == 2) v = Wmsg[(128 + k) * 128 + c];
        else               v = Wrev[(128 + k) * 128 + c];
        Wt1[idx] = (bf16_t)v;
    }
    if (idx < 256 * 128) {
        int p = idx >> 7, k = idx & 127;
        float v = (p < 128) ? Wmsg[(256 + k) * 128 + p]
                            : Wrev[(256 + k) * 128 + (p - 128)];
        WtE[idx] = (bf16_t)v;
    }
    if (idx < 128 * 128) {
        int n = idx >> 7, p = idx & 127;
        int colp = 32 * (p >> 5) + ((p >> 1) & 15) + 16 * (p & 1);
        WtU[idx] = (bf16_t)Wupd[colp * 128 + n];
    }
}

// ---------------------------------------------------------------------------
// P1: A = node @ Wt1-half. Streaming GEMM, 64 nodes x 256 cols per block,
// blockIdx.y selects F-half (0) or T-half (1). Stores interleaved uint2.
// ---------------------------------------------------------------------------
__global__ __launch_bounds__(512, 4)
void proj_node_kernel(const float* __restrict__ nodef,
                      const bf16_t* __restrict__ Wt1,
                      unsigned int* __restrict__ A_u) {
    __shared__ char lds_raw[64 * 256];  // [64][128] bf16, swizzled
    const int tid = threadIdx.x;
    const int nb = blockIdx.x * 64;
    const int by = blockIdx.y;  // 0=F, 1=T

#pragma unroll
    for (int j = 0; j < 4; ++j) {
        int linear = tid + 512 * j;
        int r = linear >> 5, q = linear & 31;
        int node = nb + r;
        f4 v = (f4){0.f, 0.f, 0.f, 0.f};
        if (node < N_NODES)
            v = *reinterpret_cast<const f4*>(nodef + (size_t)node * 128 + q * 4);
        union { bf16_t b[4]; uint2 u; } pk;
        pk.b[0] = (bf16_t)v[0]; pk.b[1] = (bf16_t)v[1];
        pk.b[2] = (bf16_t)v[2]; pk.b[3] = (bf16_t)v[3];
        int byte = (r * 256 + q * 8) ^ ((r & 7) << 4);
        *reinterpret_cast<uint2*>(lds_raw + byte) = pk.u;
    }
    __syncthreads();

    const int wv = tid >> 6;
    const int wr = wv >> 2, wc = wv & 3;
    const int lane = tid & 63;
    const int lhi = lane >> 4, llo = lane & 15;

    f32x4 acc[2][4];
#pragma unroll
    for (int m = 0; m < 2; ++m)
#pragma unroll
        for (int n = 0; n < 4; ++n)
            acc[m][n] = (f32x4){0.f, 0.f, 0.f, 0.f};

    const bf16_t* bptr[4];
#pragma unroll
    for (int n = 0; n < 4; ++n) {
        int colb = (n < 2) ? (wc * 32 + 16 * n) : (128 + wc * 32 + 16 * (n - 2));
        bptr[n] = Wt1 + (size_t)(by * 256 + colb + llo) * 128 + lhi * 8;
    }

#pragma unroll
    for (int k0 = 0; k0 < 4; ++k0) {
        bf16x8 a[2], b[4];
#pragma unroll
        for (int m = 0; m < 2; ++m) {
            int ra = wr * 32 + 16 * m + llo;
            int byte = (ra * 256 + (k0 * 32 + lhi * 8) * 2) ^ ((ra & 7) << 4);
            a[m] = *reinterpret_cast<const bf16x8*>(lds_raw + byte);
        }
#pragma unroll
        for (int n = 0; n < 4; ++n)
            b[n] = *reinterpret_cast<const bf16x8*>(bptr[n] + k0 * 32);
#pragma unroll
        for (int m = 0; m < 2; ++m)
#pragma unroll
            for (int n = 0; n < 4; ++n)
                acc[m][n] = __builtin_amdgcn_mfma_f32_16x16x32_bf16(a[m], b[n], acc[m][n], 0, 0, 0);
    }

    // interleaved store: (msgpair, revpair) adjacent -> one uint2 per (node, c)
    const int wli = wc * 16 + llo;
#pragma unroll
    for (int m = 0; m < 2; ++m) {
        int rbase = wr * 32 + 16 * m + lhi * 4;
#pragma unroll
        for (int r = 0; r < 4; ++r) {
            int node = nb + rbase + r;
            if (node < N_NODES) {
                size_t base = (size_t)node * 256 + by * 128;
                uint2 pr;
                pr.x = bfpack(acc[m][0][r], acc[m][1][r]);   // msg pair
                pr.y = bfpack(acc[m][2][r], acc[m][3][r]);   // rev pair
                *reinterpret_cast<uint2*>(A_u + base + 2 * wli) = pr;
            }
        }
    }
}

// ---------------------------------------------------------------------------
// edge_fused: per 32-edge block (256thr, 4 waves):
//   stage edgef (streaming) -> LDS, barrier,
//   ISSUE all 16 uint2 A-gathers (latency hides under MFMA),
//   MFMA K=128 (E-part), combine msg=relu(E+bm+F+T)+relu(rev...), store at inv.
// ---------------------------------------------------------------------------
__global__ __launch_bounds__(256, 4)
void edge_fused_kernel(const float* __restrict__ edgef,
                       const int* __restrict__ from_idx,
                       const int* __restrict__ to_idx,
                       const int* __restrict__ inv,
                       const unsigned int* __restrict__ A_u,
                       const bf16_t* __restrict__ WtE,
                       const float* __restrict__ b_msg,
                       const float* __restrict__ b_rev,
                       unsigned int* __restrict__ msgs_u) {
    __shared__ char lds_raw[32 * 256];  // [32][128] bf16, swizzled
    __shared__ int s_from[32], s_dst[32], s_inv[32];

    const int tid = threadIdx.x;
    const int eb = blockIdx.x * 32;

    if (tid < 32) {
        s_from[tid] = from_idx[eb + tid];
        s_dst[tid]  = to_idx[eb + tid];
        s_inv[tid]  = inv[eb + tid];
    }

    // stage: 32 rows x 32 float4 (pure streaming, no index dependence)
#pragma unroll
    for (int j = 0; j < 4; ++j) {
        int linear = tid + 256 * j;
        int r = linear >> 5, q = linear & 31;
        f4 v = *reinterpret_cast<const f4*>(edgef + (size_t)(eb + r) * 128 + q * 4);
        union { bf16_t b[4]; uint2 u; } pk;
        pk.b[0] = (bf16_t)v[0]; pk.b[1] = (bf16_t)v[1];
        pk.b[2] = (bf16_t)v[2]; pk.b[3] = (bf16_t)v[3];
        int byte = (r * 256 + q * 8) ^ ((r & 7) << 4);
        *reinterpret_cast<uint2*>(lds_raw + byte) = pk.u;
    }
    __syncthreads();

    const int wc = tid >> 6;
    const int lane = tid & 63;
    const int lhi = lane >> 4, llo = lane & 15;
    const int wli = wc * 16 + llo;

    // ---- issue all A-gathers NOW; MFMA below hides their latency ----
    uint2 gF[2][4], gT[2][4];
#pragma unroll
    for (int m = 0; m < 2; ++m) {
#pragma unroll
        for (int r = 0; r < 4; ++r) {
            int rr = 16 * m + lhi * 4 + r;
            gF[m][r] = *reinterpret_cast<const uint2*>(
                A_u + (size_t)s_from[rr] * 256 + 2 * wli);
            gT[m][r] = *reinterpret_cast<const uint2*>(
                A_u + (size_t)s_dst[rr] * 256 + 128 + 2 * wli);
        }
    }

    f32x4 acc[2][4];
#pragma unroll
    for (int m = 0; m < 2; ++m)
#pragma unroll
        for (int n = 0; n < 4; ++n)
            acc[m][n] = (f32x4){0.f, 0.f, 0.f, 0.f};

    const bf16_t* bptr[4];
#pragma unroll
    for (int n = 0; n < 4; ++n) {
        int colb = (n < 2) ? (wc * 32 + 16 * n) : (128 + wc * 32 + 16 * (n - 2));
        bptr[n] = WtE + (size_t)(colb + llo) * 128 + lhi * 8;
    }

#pragma unroll
    for (int k0 = 0; k0 < 4; ++k0) {
        bf16x8 a[2], b[4];
#pragma unroll
        for (int m = 0; m < 2; ++m) {
            int ra = 16 * m + llo;
            int byte = (ra * 256 + (k0 * 32 + lhi * 8) * 2) ^ ((ra & 7) << 4);
            a[m] = *reinterpret_cast<const bf16x8*>(lds_raw + byte);
        }
#pragma unroll
        for (int n = 0; n < 4; ++n)
            b[n] = *reinterpret_cast<const bf16x8*>(bptr[n] + k0 * 32);
#pragma unroll
        for (int m = 0; m < 2; ++m)
#pragma unroll
            for (int n = 0; n < 4; ++n)
                acc[m][n] = __builtin_amdgcn_mfma_f32_16x16x32_bf16(a[m], b[n], acc[m][n], 0, 0, 0);
    }

    const int c0 = wc * 32 + llo;
    const float bm0 = b_msg[c0], bm1 = b_msg[c0 + 16];
    const float br0 = b_rev[c0], br1 = b_rev[c0 + 16];
#pragma unroll
    for (int m = 0; m < 2; ++m) {
#pragma unroll
        for (int r = 0; r < 4; ++r) {
            int rr = 16 * m + lhi * 4 + r;
            float m0 = fmaxf(acc[m][0][r] + bm0 + bflo(gF[m][r].x) + bflo(gT[m][r].x), 0.f);
            float m1 = fmaxf(acc[m][1][r] + bm1 + bfhi(gF[m][r].x) + bfhi(gT[m][r].x), 0.f);
            float r0 = fmaxf(acc[m][2][r] + br0 + bflo(gF[m][r].y) + bflo(gT[m][r].y), 0.f);
            float r1 = fmaxf(acc[m][3][r] + br1 + bfhi(gF[m][r].y) + bfhi(gT[m][r].y), 0.f);
            msgs_u[(size_t)s_inv[rr] * 64 + wli] = bfpack(m0 + r0, m1 + r1);
        }
    }
}

// ===========================================================================
// Node update (CSR segsum of packed msgs -> MFMA w/ pi-baked WtU)
// ===========================================================================
__global__ __launch_bounds__(256, 4)
void node_upd_kernel(const unsigned int* __restrict__ msgs_u,
                     const int* __restrict__ row_start,
                     const float* __restrict__ nodef,
                     const bf16_t* __restrict__ WtU,
                     const float* __restrict__ b_upd,
                     float* __restrict__ out) {
    __shared__ char lds_raw[64 * 256];
    __shared__ int s_rs[65];

    const int tid = threadIdx.x;
    const int nb = blockIdx.x * 64;

    if (tid < 65) {
        int nid = nb + tid;
        s_rs[tid] = (nid <= N_NODES) ? row_start[nid] : N_EDGES;
    }
    __syncthreads();

    {
        const int r = tid >> 2;
        const int q = tid & 3;
        float s[32];
#pragma unroll
        for (int i = 0; i < 32; ++i) s[i] = 0.f;
        const int rs = s_rs[r], re = s_rs[r + 1];
        int e = rs;
        // unroll-by-2: 8 independent 16B loads in flight per iteration
        for (; e + 1 < re; e += 2) {
            const u32x4* p0 = reinterpret_cast<const u32x4*>(msgs_u + (size_t)e * 64 + q * 16);
            const u32x4* p1 = reinterpret_cast<const u32x4*>(msgs_u + (size_t)(e + 1) * 64 + q * 16);
            u32x4 w0[4], w1[4];
#pragma unroll
            for (int i = 0; i < 4; ++i) { w0[i] = p0[i]; w1[i] = p1[i]; }
#pragma unroll
            for (int i = 0; i < 4; ++i) {
                s[8*i+0] += bflo(w0[i][0]) + bflo(w1[i][0]);
                s[8*i+1] += bfhi(w0[i][0]) + bfhi(w1[i][0]);
                s[8*i+2] += bflo(w0[i][1]) + bflo(w1[i][1]);
                s[8*i+3] += bfhi(w0[i][1]) + bfhi(w1[i][1]);
                s[8*i+4] += bflo(w0[i][2]) + bflo(w1[i][2]);
                s[8*i+5] += bfhi(w0[i][2]) + bfhi(w1[i][2]);
                s[8*i+6] += bflo(w0[i][3]) + bflo(w1[i][3]);
                s[8*i+7] += bfhi(w0[i][3]) + bfhi(w1[i][3]);
            }
        }
        if (e < re) {
            const u32x4* p = reinterpret_cast<const u32x4*>(msgs_u + (size_t)e * 64 + q * 16);
#pragma unroll
            for (int i = 0; i < 4; ++i) {
                u32x4 w = p[i];
                s[8*i+0] += bflo(w[0]); s[8*i+1] += bfhi(w[0]);
                s[8*i+2] += bflo(w[1]); s[8*i+3] += bfhi(w[1]);
                s[8*i+4] += bflo(w[2]); s[8*i+5] += bfhi(w[2]);
                s[8*i+6] += bflo(w[3]); s[8*i+7] += bfhi(w[3]);
            }
        }
#pragma unroll
        for (int i = 0; i < 4; ++i) {
            union { bf16_t b[8]; u32x4 u; } pk;
#pragma unroll
            for (int w = 0; w < 8; ++w) pk.b[w] = (bf16_t)s[8*i + w];
            int byte = (r * 256 + q * 64 + i * 16) ^ ((r & 7) << 4);
            *reinterpret_cast<u32x4*>(lds_raw + byte) = pk.u;
        }
    }
    __syncthreads();

    const int wv = tid >> 6;
    const int lane = tid & 63;
    const int lhi = lane >> 4, llo = lane & 15;

    f32x4 acc[4][2];
#pragma unroll
    for (int m = 0; m < 4; ++m)
#pragma unroll
        for (int n = 0; n < 2; ++n)
            acc[m][n] = (f32x4){0.f, 0.f, 0.f, 0.f};

#pragma unroll
    for (int k0 = 0; k0 < 4; ++k0) {
        bf16x8 a[4], b[2];
#pragma unroll
        for (int m = 0; m < 4; ++m) {
            int ra = 16 * m + llo;
            int byte = (ra * 256 + (k0 * 32 + lhi * 8) * 2) ^ ((ra & 7) << 4);
            a[m] = *reinterpret_cast<const bf16x8*>(lds_raw + byte);
        }
#pragma unroll
        for (int n = 0; n < 2; ++n) {
            int col = wv * 32 + 16 * n + llo;
            b[n] = *reinterpret_cast<const bf16x8*>(WtU + (size_t)col * 128 + k0 * 32 + lhi * 8);
        }
#pragma unroll
        for (int m = 0; m < 4; ++m)
#pragma unroll
            for (int n = 0; n < 2; ++n)
                acc[m][n] = __builtin_amdgcn_mfma_f32_16x16x32_bf16(a[m], b[n], acc[m][n], 0, 0, 0);
    }

#pragma unroll
    for (int m = 0; m < 4; ++m) {
        int rbase = 16 * m + lhi * 4;
#pragma unroll
        for (int r = 0; r < 4; ++r) {
            int i = nb + rbase + r;
            if (i < N_NODES) {
#pragma unroll
                for (int n = 0; n < 2; ++n) {
                    int c = wv * 32 + 16 * n + llo;
                    out[(size_t)i * 128 + c] =
                        nodef[(size_t)i * 128 + c]
                        + fmaxf(acc[m][n][r] + b_upd[c], 0.f);
                }
            }
        }
    }
}

// ===========================================================================
// OLD PATH fallback (only if ws too small for factored path)
// ===========================================================================
__global__ __launch_bounds__(256)
void convert_nodef_kernel(const float* __restrict__ nodef,
                          unsigned short* __restrict__ nodef_bf) {
    int i = blockIdx.x * 256 + threadIdx.x;
    if (i < N_NODES * 32) {
        f4 v = *reinterpret_cast<const f4*>(nodef + (size_t)i * 4);
        union { bf16_t b[4]; unsigned long long ll; } pk;
        pk.b[0] = (bf16_t)v[0]; pk.b[1] = (bf16_t)v[1];
        pk.b[2] = (bf16_t)v[2]; pk.b[3] = (bf16_t)v[3];
        *reinterpret_cast<unsigned long long*>(nodef_bf + (size_t)i * 4) = pk.ll;
    }
}

__global__ void prep_w_old(const float* __restrict__ Wmsg,
                           const float* __restrict__ Wrev,
                           const float* __restrict__ Wupd,
                           bf16_t* __restrict__ WtAB,
                           bf16_t* __restrict__ WtU) {
    int idx = blockIdx.x * 256 + threadIdx.x;
    if (idx < 256 * 384) {
        int n = idx / 384;
        int k = idx - n * 384;
        float v = (n < 128) ? Wmsg[k * 128 + n] : Wrev[k * 128 + (n - 128)];
        WtAB[idx] = (bf16_t)v;
    }
    if (idx < 128 * 128) {
        int n = idx >> 7, p = idx & 127;
        int colp = 32 * (p >> 5) + ((p >> 1) & 15) + 16 * (p & 1);
        WtU[idx] = (bf16_t)Wupd[colp * 128 + n];
    }
}

__global__ __launch_bounds__(512, 4)
void edge_msg_old_kernel(const unsigned short* __restrict__ nodef_bf,
                         const float* __restrict__ edgef,
                         const int* __restrict__ from_idx,
                         const int* __restrict__ to_idx,
                         const int* __restrict__ inv,
                         const bf16_t* __restrict__ WtAB,
                         const float* __restrict__ b_msg,
                         const float* __restrict__ b_rev,
                         unsigned int* __restrict__ msgs_u) {
    __shared__ char lds_raw[64 * 384];
    __shared__ int s_from[64], s_dst[64], s_inv[64];

    const int tid = threadIdx.x;
    const int eb = blockIdx.x * 64;

    if (tid < 64) {
        s_from[tid] = from_idx[eb + tid];
        s_dst[tid]  = to_idx[eb + tid];
        s_inv[tid]  = inv[eb + tid];
    }

    const int wv = tid >> 6;
    const int wr = wv >> 2, wc = wv & 3;
    const int lane = tid & 63;
    const int lhi = lane >> 4, llo = lane & 15;

    f32x4 acc[2][4];
#pragma unroll
    for (int m = 0; m < 2; ++m)
#pragma unroll
        for (int n = 0; n < 4; ++n)
            acc[m][n] = (f32x4){0.f, 0.f, 0.f, 0.f};

    const bf16_t* bptr[4];
#pragma unroll
    for (int n = 0; n < 4; ++n) {
        int colb = (n < 2) ? (wc * 32 + 16 * n) : (128 + wc * 32 + 16 * (n - 2));
        bptr[n] = WtAB + (size_t)(colb + llo) * 384 + lhi * 8;
    }

    __syncthreads();

#pragma unroll
    for (int j = 0; j < 3; ++j) {
        int linear = tid + 512 * j;
        int r = linear / 24;
        int q = linear - r * 24;
        const u32x4* src = (q < 16)
            ? reinterpret_cast<const u32x4*>(nodef_bf + (size_t)s_from[r] * 128) + q
            : reinterpret_cast<const u32x4*>(nodef_bf + (size_t)s_dst[r] * 128) + (q - 16);
        u32x4 v = *src;
        int byte = (r * 384 + q * 16) ^ ((r & 7) << 4);
        *reinterpret_cast<u32x4*>(lds_raw + byte) = v;
    }
    __syncthreads();

#pragma unroll
    for (int k0 = 0; k0 < 6; ++k0) {
        bf16x8 a[2], b[4];
#pragma unroll
        for (int m = 0; m < 2; ++m) {
            int ra = wr * 32 + 16 * m + llo;
            int byte = (ra * 384 + k0 * 64 + lhi * 16) ^ ((ra & 7) << 4);
            a[m] = *reinterpret_cast<const bf16x8*>(lds_raw + byte);
        }
#pragma unroll
        for (int n = 0; n < 4; ++n)
            b[n] = *reinterpret_cast<const bf16x8*>(bptr[n] + k0 * 32);
#pragma unroll
        for (int m = 0; m < 2; ++m)
#pragma unroll
            for (int n = 0; n < 4; ++n)
                acc[m][n] = __builtin_amdgcn_mfma_f32_16x16x32_bf16(a[m], b[n], acc[m][n], 0, 0, 0);
    }
    __syncthreads();

#pragma unroll
    for (int j = 0; j < 3; ++j) {
        int linear = tid + 512 * j;
        int r = linear / 24;
        int qq = linear - r * 24;
        u32x4 w;
        if (qq < 8) {
            w = *(reinterpret_cast<const u32x4*>(nodef_bf + (size_t)s_dst[r] * 128) + 8 + qq);
        } else {
            int c = qq - 8;
            const f4* ep = reinterpret_cast<const f4*>(edgef + (size_t)(eb + r) * 128 + c * 8);
            f4 v0 = ep[0];
            f4 v1 = ep[1];
            union { bf16_t b[8]; u32x4 u; } pk;
            pk.b[0] = (bf16_t)v0[0]; pk.b[1] = (bf16_t)v0[1];
            pk.b[2] = (bf16_t)v0[2]; pk.b[3] = (bf16_t)v0[3];
            pk.b[4] = (bf16_t)v1[0]; pk.b[5] = (bf16_t)v1[1];
            pk.b[6] = (bf16_t)v1[2]; pk.b[7] = (bf16_t)v1[3];
            w = pk.u;
        }
        int byte = (r * 384 + qq * 16) ^ ((r & 7) << 4);
        *reinterpret_cast<u32x4*>(lds_raw + byte) = w;
    }
    __syncthreads();

#pragma unroll
    for (int k0 = 0; k0 < 6; ++k0) {
        bf16x8 a[2], b[4];
#pragma unroll
        for (int m = 0; m < 2; ++m) {
            int ra = wr * 32 + 16 * m + llo;
            int byte = (ra * 384 + k0 * 64 + lhi * 16) ^ ((ra & 7) << 4);
            a[m] = *reinterpret_cast<const bf16x8*>(lds_raw + byte);
        }
#pragma unroll
        for (int n = 0; n < 4; ++n)
            b[n] = *reinterpret_cast<const bf16x8*>(bptr[n] + (6 + k0) * 32);
#pragma unroll
        for (int m = 0; m < 2; ++m)
#pragma unroll
            for (int n = 0; n < 4; ++n)
                acc[m][n] = __builtin_amdgcn_mfma_f32_16x16x32_bf16(a[m], b[n], acc[m][n], 0, 0, 0);
    }

    const int c0 = wc * 32 + llo;
    const float bm0 = b_msg[c0], br0 = b_rev[c0];
    const float bm1 = b_msg[c0 + 16], br1 = b_rev[c0 + 16];
#pragma unroll
    for (int m = 0; m < 2; ++m) {
        int rbase = wr * 32 + 16 * m + lhi * 4;
#pragma unroll
        for (int r = 0; r < 4; ++r) {
            float v0 = fmaxf(acc[m][0][r] + bm0, 0.f) + fmaxf(acc[m][2][r] + br0, 0.f);
            float v1 = fmaxf(acc[m][1][r] + bm1, 0.f) + fmaxf(acc[m][3][r] + br1, 0.f);
            msgs_u[(size_t)s_inv[rbase + r] * 64 + wc * 16 + llo] = bfpack(v0, v1);
        }
    }
}

// ===========================================================================
extern "C" void kernel_launch(void* const* d_in, const int* in_sizes, int n_in,
                              void* d_out, int out_size, void* d_ws, size_t ws_size,
                              hipStream_t stream) {
    const float* nodef    = (const float*)d_in[0];
    const float* edgef    = (const float*)d_in[1];
    const int*   from_idx = (const int*)d_in[2];
    const int*   to_idx   = (const int*)d_in[3];
    const float* Wmsg     = (const float*)d_in[4];
    const float* bmsg     = (const float*)d_in[5];
    const float* Wrev     = (const float*)d_in[6];
    const float* brev     = (const float*)d_in[7];
    const float* Wupd     = (const float*)d_in[8];
    const float* bupd     = (const float*)d_in[9];
    float* out = (float*)d_out;
    char* ws = (char*)d_ws;

    if (ws_size >= 271000000) {
        // ---------------- factored GEMM path ----------------
        unsigned int* A_u      = (unsigned int*)ws;               // 102,400,000
        unsigned int* msgs_u   = (unsigned int*)(ws + 102400000); // 163,840,000
        bf16_t*       Wt1      = (bf16_t*)(ws + 266240000);       // 131,072
        bf16_t*       WtE      = (bf16_t*)(ws + 266371072);       // 65,536
        bf16_t*       WtU      = (bf16_t*)(ws + 266436608);       // 32,768
        int*          hist     = (int*)(ws + 266469376);          // 400,000
        int*          cursor   = (int*)(ws + 266869376);          // 400,000
        int*          rowstart = (int*)(ws + 267269376);          // 400,016
        int*          inv      = (int*)(ws + 267669392);          // 2,560,000
        int*          bsum     = (int*)(ws + 270229392);          // 400
        int*          bbase    = (int*)(ws + 270229792);          // 400

        hipMemsetAsync(hist, 0, (size_t)N_NODES * sizeof(int), stream);
        prep_w_new<<<256, 256, 0, stream>>>(Wmsg, Wrev, Wupd, Wt1, WtE, WtU);
        hist_kernel<<<(N_EDGES + 255) / 256, 256, 0, stream>>>(to_idx, hist);
        scan_reduce_kernel<<<100, 1024, 0, stream>>>(hist, bsum);
        scan_base_kernel<<<1, 128, 0, stream>>>(bsum, bbase);
        scan_final_kernel<<<100, 1024, 0, stream>>>(hist, bbase, cursor, rowstart);
        inv_scatter_kernel<<<(N_EDGES + 255) / 256, 256, 0, stream>>>(to_idx, cursor, inv);
        proj_node_kernel<<<dim3((N_NODES + 63) / 64, 2), 512, 0, stream>>>(nodef, Wt1, A_u);
        edge_fused_kernel<<<N_EDGES / 32, 256, 0, stream>>>(
            edgef, from_idx, to_idx, inv, A_u, WtE, bmsg, brev, msgs_u);
        node_upd_kernel<<<(N_NODES + 63) / 64, 256, 0, stream>>>(
            msgs_u, rowstart, nodef, WtU, bupd, out);
    } else {
        // ---------------- OLD PATH (r8) ----------------
        unsigned int*   msgs_u   = (unsigned int*)ws;                 // 163,840,000
        bf16_t*         WtAB     = (bf16_t*)(ws + 163840000);         // 196,608
        bf16_t*         WtU      = (bf16_t*)(ws + 164036608);         // 32,768
        unsigned short* nodef_bf = (unsigned short*)(ws + 164069376); // 25,600,000
        int*            hist     = (int*)(ws + 189669376);            // 400,000
        int*            cursor   = (int*)(ws + 190069376);            // 400,000
        int*            rowstart = (int*)(ws + 190469376);            // 400,016
        int*            inv      = (int*)(ws + 190869392);            // 2,560,000
        int*            bsum     = (int*)(ws + 193429392);            // 400
        int*            bbase    = (int*)(ws + 193429792);            // 400

        hipMemsetAsync(hist, 0, (size_t)N_NODES * sizeof(int), stream);
        convert_nodef_kernel<<<12500, 256, 0, stream>>>(nodef, nodef_bf);
        prep_w_old<<<384, 256, 0, stream>>>(Wmsg, Wrev, Wupd, WtAB, WtU);
        hist_kernel<<<(N_EDGES + 255) / 256, 256, 0, stream>>>(to_idx, hist);
        scan_reduce_kernel<<<100, 1024, 0, stream>>>(hist, bsum);
        scan_base_kernel<<<1, 128, 0, stream>>>(bsum, bbase);
        scan_final_kernel<<<100, 1024, 0, stream>>>(hist, bbase, cursor, rowstart);
        inv_scatter_kernel<<<(N_EDGES + 255) / 256, 256, 0, stream>>>(to_idx, cursor, inv);
        edge_msg_old_kernel<<<N_EDGES / 64, 512, 0, stream>>>(
            nodef_bf, edgef, from_idx, to_idx, inv, WtAB, bmsg, brev, msgs_u);
        node_upd_kernel<<<(N_NODES + 63) / 64, 256, 0, stream>>>(
            msgs_u, rowstart, nodef, WtU, bupd, out);
    }
}

// Round 11
// 457.458 us; speedup vs baseline: 1.5112x; 1.0006x over previous
//
#include <hip/hip_runtime.h>
#include <hip/hip_bf16.h>

#define N_NODES 100000
#define N_EDGES 640000

typedef __bf16 bf16_t;
typedef __bf16 bf16x8 __attribute__((ext_vector_type(8)));
typedef float f32x4 __attribute__((ext_vector_type(4)));
typedef float f4 __attribute__((ext_vector_type(4)));
typedef unsigned int u32x4 __attribute__((ext_vector_type(4)));

__device__ __forceinline__ float bflo(unsigned int u) { return __uint_as_float(u << 16); }
__device__ __forceinline__ float bfhi(unsigned int u) { return __uint_as_float(u & 0xffff0000u); }
__device__ __forceinline__ unsigned int bfpack(float a, float b) {
    union { bf16_t h[2]; unsigned int u; } pk;
    pk.h[0] = (bf16_t)a; pk.h[1] = (bf16_t)b;
    return pk.u;
}

// ===========================================================================
// CSR build (hist -> hierarchical scan -> inverse permutation)
// ===========================================================================
__global__ void hist_kernel(const int* __restrict__ to_idx, int* __restrict__ hist) {
    int e = blockIdx.x * 256 + threadIdx.x;
    if (e < N_EDGES) atomicAdd(&hist[to_idx[e]], 1);
}

#define SCAN_CH 1000  // N_NODES = 100 blocks x 1000

__global__ __launch_bounds__(1024)
void scan_reduce_kernel(const int* __restrict__ hist, int* __restrict__ bsum) {
    __shared__ int red[1024];
    int b = blockIdx.x, t = threadIdx.x;
    int v = (t < SCAN_CH) ? hist[b * SCAN_CH + t] : 0;
    red[t] = v;
    __syncthreads();
    for (int off = 512; off > 0; off >>= 1) {
        if (t < off) red[t] += red[t + off];
        __syncthreads();
    }
    if (t == 0) bsum[b] = red[0];
}

__global__ __launch_bounds__(128)
void scan_base_kernel(const int* __restrict__ bsum, int* __restrict__ bbase) {
    __shared__ int s[128];
    int t = threadIdx.x;
    int v = (t < 100) ? bsum[t] : 0;
    s[t] = v;
    __syncthreads();
    for (int off = 1; off < 128; off <<= 1) {
        int u = (t >= off) ? s[t - off] : 0;
        __syncthreads();
        s[t] += u;
        __syncthreads();
    }
    if (t < 100) bbase[t] = s[t] - v;
}

__global__ __launch_bounds__(1024)
void scan_final_kernel(const int* __restrict__ hist,
                       const int* __restrict__ bbase,
                       int* __restrict__ cursor,
                       int* __restrict__ row_start) {
    __shared__ int s[1024];
    int b = blockIdx.x, t = threadIdx.x;
    int v = (t < SCAN_CH) ? hist[b * SCAN_CH + t] : 0;
    s[t] = v;
    __syncthreads();
    for (int off = 1; off < 1024; off <<= 1) {
        int u = (t >= off) ? s[t - off] : 0;
        __syncthreads();
        s[t] += u;
        __syncthreads();
    }
    int excl = bbase[b] + s[t] - v;
    if (t < SCAN_CH) {
        cursor[b * SCAN_CH + t] = excl;
        row_start[b * SCAN_CH + t] = excl;
    }
    if (b == 99 && t == SCAN_CH - 1) row_start[N_NODES] = excl + v;
}

__global__ void inv_scatter_kernel(const int* __restrict__ to_idx,
                                   int* __restrict__ cursor,
                                   int* __restrict__ inv) {
    int e = blockIdx.x * 256 + threadIdx.x;
    if (e < N_EDGES) {
        int pos = atomicAdd(&cursor[to_idx[e]], 1);
        inv[e] = pos;
    }
}

// ===========================================================================
// Factored GEMM path. A[100K][256 u32] interleaved (msgpair, revpair) uint2.
// Wt1 [512][128], WtE [256][128], WtU [128][128] pi-baked (as r10).
// ===========================================================================
__global__ void prep_w_new(const float* __restrict__ Wmsg,
                           const float* __restrict__ Wrev,
                           const float* __restrict__ Wupd,
                           bf16_t* __restrict__ Wt1,
                           bf16_t* __restrict__ WtE,
                           bf16_t* __restrict__ WtU) {
    int idx = blockIdx.x * 256 + threadIdx.x;
    if (idx < 512 * 128) {
        int p = idx >> 7, k = idx & 127;
        int blk = p >> 7, c = p & 127;
        float v;
        if (blk == 0)      v = Wmsg[k * 128 + c];
        else if (blk == 1) v = Wrev[k * 128 + c];
        else if (blk == 2) v = Wmsg[(128 + k) * 128 + c];
        else               v = Wrev[(128 + k) * 128 + c];
        Wt1[idx] = (bf16_t)v;
    }
    if (idx < 256 * 128) {
        int p = idx >> 7, k = idx & 127;
        float v = (p < 128) ? Wmsg[(256 + k) * 128 + p]
                            : Wrev[(256 + k) * 128 + (p - 128)];
        WtE[idx] = (bf16_t)v;
    }
    if (idx < 128 * 128) {
        int n = idx >> 7, p = idx & 127;
        int colp = 32 * (p >> 5) + ((p >> 1) & 15) + 16 * (p & 1);
        WtU[idx] = (bf16_t)Wupd[colp * 128 + n];
    }
}

// ---------------------------------------------------------------------------
// P1: A = node @ Wt1-half (streaming GEMM), stores interleaved uint2.
// ---------------------------------------------------------------------------
__global__ __launch_bounds__(512, 4)
void proj_node_kernel(const float* __restrict__ nodef,
                      const bf16_t* __restrict__ Wt1,
                      unsigned int* __restrict__ A_u) {
    __shared__ char lds_raw[64 * 256];  // [64][128] bf16, swizzled
    const int tid = threadIdx.x;
    const int nb = blockIdx.x * 64;
    const int by = blockIdx.y;  // 0=F, 1=T

#pragma unroll
    for (int j = 0; j < 4; ++j) {
        int linear = tid + 512 * j;
        int r = linear >> 5, q = linear & 31;
        int node = nb + r;
        f4 v = (f4){0.f, 0.f, 0.f, 0.f};
        if (node < N_NODES)
            v = *reinterpret_cast<const f4*>(nodef + (size_t)node * 128 + q * 4);
        union { bf16_t b[4]; uint2 u; } pk;
        pk.b[0] = (bf16_t)v[0]; pk.b[1] = (bf16_t)v[1];
        pk.b[2] = (bf16_t)v[2]; pk.b[3] = (bf16_t)v[3];
        int byte = (r * 256 + q * 8) ^ ((r & 7) << 4);
        *reinterpret_cast<uint2*>(lds_raw + byte) = pk.u;
    }
    __syncthreads();

    const int wv = tid >> 6;
    const int wr = wv >> 2, wc = wv & 3;
    const int lane = tid & 63;
    const int lhi = lane >> 4, llo = lane & 15;

    f32x4 acc[2][4];
#pragma unroll
    for (int m = 0; m < 2; ++m)
#pragma unroll
        for (int n = 0; n < 4; ++n)
            acc[m][n] = (f32x4){0.f, 0.f, 0.f, 0.f};

    const bf16_t* bptr[4];
#pragma unroll
    for (int n = 0; n < 4; ++n) {
        int colb = (n < 2) ? (wc * 32 + 16 * n) : (128 + wc * 32 + 16 * (n - 2));
        bptr[n] = Wt1 + (size_t)(by * 256 + colb + llo) * 128 + lhi * 8;
    }

#pragma unroll
    for (int k0 = 0; k0 < 4; ++k0) {
        bf16x8 a[2], b[4];
#pragma unroll
        for (int m = 0; m < 2; ++m) {
            int ra = wr * 32 + 16 * m + llo;
            int byte = (ra * 256 + (k0 * 32 + lhi * 8) * 2) ^ ((ra & 7) << 4);
            a[m] = *reinterpret_cast<const bf16x8*>(lds_raw + byte);
        }
#pragma unroll
        for (int n = 0; n < 4; ++n)
            b[n] = *reinterpret_cast<const bf16x8*>(bptr[n] + k0 * 32);
#pragma unroll
        for (int m = 0; m < 2; ++m)
#pragma unroll
            for (int n = 0; n < 4; ++n)
                acc[m][n] = __builtin_amdgcn_mfma_f32_16x16x32_bf16(a[m], b[n], acc[m][n], 0, 0, 0);
    }

    const int wli = wc * 16 + llo;
#pragma unroll
    for (int m = 0; m < 2; ++m) {
        int rbase = wr * 32 + 16 * m + lhi * 4;
#pragma unroll
        for (int r = 0; r < 4; ++r) {
            int node = nb + rbase + r;
            if (node < N_NODES) {
                size_t base = (size_t)node * 256 + by * 128;
                uint2 pr;
                pr.x = bfpack(acc[m][0][r], acc[m][1][r]);   // msg pair
                pr.y = bfpack(acc[m][2][r], acc[m][3][r]);   // rev pair
                *reinterpret_cast<uint2*>(A_u + base + 2 * wli) = pr;
            }
        }
    }
}

// ---------------------------------------------------------------------------
// edge_fused, 4-tile pipelined. Per 256-thr block: 4 tiles x 32 edges.
// vmcnt-ordering-aware issue order per tile (vmcnt retires IN ISSUE ORDER):
//   1. b(k0,k1) loads        <- OLDER than gathers: mfma01's wait won't drain them
//   2. A-gathers
//   3. stage loads tile t+1  <- fire, consumed late
//   4. mfma k0,k1 (LDS a-frags; gathers fly underneath)
//   5. b(k2,k3) loads, 6. mfma k2,k3 (this wait drains gathers, mostly returned)
//   7. ds_write stage -> buf[cur^1]   8. epilogue combine + scatter store
//   9. barrier
// ---------------------------------------------------------------------------
__global__ __launch_bounds__(256, 4)
void edge_fused_kernel(const float* __restrict__ edgef,
                       const int* __restrict__ from_idx,
                       const int* __restrict__ to_idx,
                       const int* __restrict__ inv,
                       const unsigned int* __restrict__ A_u,
                       const bf16_t* __restrict__ WtE,
                       const float* __restrict__ b_msg,
                       const float* __restrict__ b_rev,
                       unsigned int* __restrict__ msgs_u) {
    __shared__ char lds_raw[2][8192];   // 2 x [32][128] bf16, XOR-swizzled
    __shared__ int s_from[128], s_dst[128], s_inv[128];

    const int tid = threadIdx.x;
    const size_t eb0 = (size_t)blockIdx.x * 128;

    if (tid < 128) {
        s_from[tid] = from_idx[eb0 + tid];
        s_dst[tid]  = to_idx[eb0 + tid];
        s_inv[tid]  = inv[eb0 + tid];
    }

    const int wc = tid >> 6;
    const int lane = tid & 63;
    const int lhi = lane >> 4, llo = lane & 15;
    const int wli = wc * 16 + llo;

    const bf16_t* bptr[4];
#pragma unroll
    for (int n = 0; n < 4; ++n) {
        int colb = (n < 2) ? (wc * 32 + 16 * n) : (128 + wc * 32 + 16 * (n - 2));
        bptr[n] = WtE + (size_t)(colb + llo) * 128 + lhi * 8;
    }

    const int c0 = wc * 32 + llo;
    const float bm0 = b_msg[c0], bm1 = b_msg[c0 + 16];
    const float br0 = b_rev[c0], br1 = b_rev[c0 + 16];

    // ---- prologue: stage tile 0 ----
    f4 st[4];
#pragma unroll
    for (int j = 0; j < 4; ++j) {
        int lin = tid + 256 * j, r = lin >> 5, q = lin & 31;
        st[j] = *reinterpret_cast<const f4*>(edgef + (eb0 + r) * 128 + q * 4);
    }
#pragma unroll
    for (int j = 0; j < 4; ++j) {
        int lin = tid + 256 * j, r = lin >> 5, q = lin & 31;
        union { bf16_t b[4]; uint2 u; } pk;
        pk.b[0] = (bf16_t)st[j][0]; pk.b[1] = (bf16_t)st[j][1];
        pk.b[2] = (bf16_t)st[j][2]; pk.b[3] = (bf16_t)st[j][3];
        int byte = (r * 256 + q * 8) ^ ((r & 7) << 4);
        *reinterpret_cast<uint2*>(&lds_raw[0][0] + byte) = pk.u;
    }
    __syncthreads();

#pragma unroll
    for (int t = 0; t < 4; ++t) {
        const int cur = t & 1;

        // 1. B-frags ksteps 0,1 (older than gathers on the vm queue)
        bf16x8 bA[2][4];
#pragma unroll
        for (int k0 = 0; k0 < 2; ++k0)
#pragma unroll
            for (int n = 0; n < 4; ++n)
                bA[k0][n] = *reinterpret_cast<const bf16x8*>(bptr[n] + k0 * 32);

        // 2. A-gathers for tile t
        uint2 gF[2][4], gT[2][4];
#pragma unroll
        for (int m = 0; m < 2; ++m)
#pragma unroll
            for (int r = 0; r < 4; ++r) {
                int rr = t * 32 + 16 * m + lhi * 4 + r;
                gF[m][r] = *reinterpret_cast<const uint2*>(
                    A_u + (size_t)s_from[rr] * 256 + 2 * wli);
                gT[m][r] = *reinterpret_cast<const uint2*>(
                    A_u + (size_t)s_dst[rr] * 256 + 128 + 2 * wli);
            }

        // 3. stage loads for tile t+1 (fire now, consume at step 7)
        if (t < 3) {
#pragma unroll
            for (int j = 0; j < 4; ++j) {
                int lin = tid + 256 * j, r = lin >> 5, q = lin & 31;
                st[j] = *reinterpret_cast<const f4*>(
                    edgef + (eb0 + (size_t)(t + 1) * 32 + r) * 128 + q * 4);
            }
        }

        // 4. MFMA ksteps 0,1 — only waits bA (older); gathers keep flying
        f32x4 acc[2][4];
#pragma unroll
        for (int m = 0; m < 2; ++m)
#pragma unroll
            for (int n = 0; n < 4; ++n)
                acc[m][n] = (f32x4){0.f, 0.f, 0.f, 0.f};
#pragma unroll
        for (int k0 = 0; k0 < 2; ++k0) {
            bf16x8 a[2];
#pragma unroll
            for (int m = 0; m < 2; ++m) {
                int ra = 16 * m + llo;
                int byte = (ra * 256 + (k0 * 32 + lhi * 8) * 2) ^ ((ra & 7) << 4);
                a[m] = *reinterpret_cast<const bf16x8*>(&lds_raw[cur][0] + byte);
            }
#pragma unroll
            for (int m = 0; m < 2; ++m)
#pragma unroll
                for (int n = 0; n < 4; ++n)
                    acc[m][n] = __builtin_amdgcn_mfma_f32_16x16x32_bf16(a[m], bA[k0][n], acc[m][n], 0, 0, 0);
        }

        // 5. B-frags ksteps 2,3
#pragma unroll
        for (int k0 = 0; k0 < 2; ++k0)
#pragma unroll
            for (int n = 0; n < 4; ++n)
                bA[k0][n] = *reinterpret_cast<const bf16x8*>(bptr[n] + (2 + k0) * 32);

        // 6. MFMA ksteps 2,3
#pragma unroll
        for (int k0 = 0; k0 < 2; ++k0) {
            bf16x8 a[2];
#pragma unroll
            for (int m = 0; m < 2; ++m) {
                int ra = 16 * m + llo;
                int byte = (ra * 256 + ((2 + k0) * 32 + lhi * 8) * 2) ^ ((ra & 7) << 4);
                a[m] = *reinterpret_cast<const bf16x8*>(&lds_raw[cur][0] + byte);
            }
#pragma unroll
            for (int m = 0; m < 2; ++m)
#pragma unroll
                for (int n = 0; n < 4; ++n)
                    acc[m][n] = __builtin_amdgcn_mfma_f32_16x16x32_bf16(a[m], bA[k0][n], acc[m][n], 0, 0, 0);
        }

        // 7. write staged tile t+1 into the other buffer
        if (t < 3) {
#pragma unroll
            for (int j = 0; j < 4; ++j) {
                int lin = tid + 256 * j, r = lin >> 5, q = lin & 31;
                union { bf16_t b[4]; uint2 u; } pk;
                pk.b[0] = (bf16_t)st[j][0]; pk.b[1] = (bf16_t)st[j][1];
                pk.b[2] = (bf16_t)st[j][2]; pk.b[3] = (bf16_t)st[j][3];
                int byte = (r * 256 + q * 8) ^ ((r & 7) << 4);
                *reinterpret_cast<uint2*>(&lds_raw[cur ^ 1][0] + byte) = pk.u;
            }
        }

        // 8. epilogue: combine (gathers drained by step 5/6 waits), store
#pragma unroll
        for (int m = 0; m < 2; ++m)
#pragma unroll
            for (int r = 0; r < 4; ++r) {
                int rr = t * 32 + 16 * m + lhi * 4 + r;
                float m0 = fmaxf(acc[m][0][r] + bm0 + bflo(gF[m][r].x) + bflo(gT[m][r].x), 0.f);
                float m1 = fmaxf(acc[m][1][r] + bm1 + bfhi(gF[m][r].x) + bfhi(gT[m][r].x), 0.f);
                float r0 = fmaxf(acc[m][2][r] + br0 + bflo(gF[m][r].y) + bflo(gT[m][r].y), 0.f);
                float r1 = fmaxf(acc[m][3][r] + br1 + bfhi(gF[m][r].y) + bfhi(gT[m][r].y), 0.f);
                msgs_u[(size_t)s_inv[rr] * 64 + wli] = bfpack(m0 + r0, m1 + r1);
            }

        // 9. barrier: buf[cur^1] writes visible; buf[cur] free for overwrite
        __syncthreads();
    }
}

// ===========================================================================
// Node update (CSR segsum of packed msgs -> MFMA w/ pi-baked WtU)
// ===========================================================================
__global__ __launch_bounds__(256, 4)
void node_upd_kernel(const unsigned int* __restrict__ msgs_u,
                     const int* __restrict__ row_start,
                     const float* __restrict__ nodef,
                     const bf16_t* __restrict__ WtU,
                     const float* __restrict__ b_upd,
                     float* __restrict__ out) {
    __shared__ char lds_raw[64 * 256];
    __shared__ int s_rs[65];

    const int tid = threadIdx.x;
    const int nb = blockIdx.x * 64;

    if (tid < 65) {
        int nid = nb + tid;
        s_rs[tid] = (nid <= N_NODES) ? row_start[nid] : N_EDGES;
    }
    __syncthreads();

    {
        const int r = tid >> 2;
        const int q = tid & 3;
        float s[32];
#pragma unroll
        for (int i = 0; i < 32; ++i) s[i] = 0.f;
        const int rs = s_rs[r], re = s_rs[r + 1];
        int e = rs;
        for (; e + 1 < re; e += 2) {
            const u32x4* p0 = reinterpret_cast<const u32x4*>(msgs_u + (size_t)e * 64 + q * 16);
            const u32x4* p1 = reinterpret_cast<const u32x4*>(msgs_u + (size_t)(e + 1) * 64 + q * 16);
            u32x4 w0[4], w1[4];
#pragma unroll
            for (int i = 0; i < 4; ++i) { w0[i] = p0[i]; w1[i] = p1[i]; }
#pragma unroll
            for (int i = 0; i < 4; ++i) {
                s[8*i+0] += bflo(w0[i][0]) + bflo(w1[i][0]);
                s[8*i+1] += bfhi(w0[i][0]) + bfhi(w1[i][0]);
                s[8*i+2] += bflo(w0[i][1]) + bflo(w1[i][1]);
                s[8*i+3] += bfhi(w0[i][1]) + bfhi(w1[i][1]);
                s[8*i+4] += bflo(w0[i][2]) + bflo(w1[i][2]);
                s[8*i+5] += bfhi(w0[i][2]) + bfhi(w1[i][2]);
                s[8*i+6] += bflo(w0[i][3]) + bflo(w1[i][3]);
                s[8*i+7] += bfhi(w0[i][3]) + bfhi(w1[i][3]);
            }
        }
        if (e < re) {
            const u32x4* p = reinterpret_cast<const u32x4*>(msgs_u + (size_t)e * 64 + q * 16);
#pragma unroll
            for (int i = 0; i < 4; ++i) {
                u32x4 w = p[i];
                s[8*i+0] += bflo(w[0]); s[8*i+1] += bfhi(w[0]);
                s[8*i+2] += bflo(w[1]); s[8*i+3] += bfhi(w[1]);
                s[8*i+4] += bflo(w[2]); s[8*i+5] += bfhi(w[2]);
                s[8*i+6] += bflo(w[3]); s[8*i+7] += bfhi(w[3]);
            }
        }
#pragma unroll
        for (int i = 0; i < 4; ++i) {
            union { bf16_t b[8]; u32x4 u; } pk;
#pragma unroll
            for (int w = 0; w < 8; ++w) pk.b[w] = (bf16_t)s[8*i + w];
            int byte = (r * 256 + q * 64 + i * 16) ^ ((r & 7) << 4);
            *reinterpret_cast<u32x4*>(lds_raw + byte) = pk.u;
        }
    }
    __syncthreads();

    const int wv = tid >> 6;
    const int lane = tid & 63;
    const int lhi = lane >> 4, llo = lane & 15;

    f32x4 acc[4][2];
#pragma unroll
    for (int m = 0; m < 4; ++m)
#pragma unroll
        for (int n = 0; n < 2; ++n)
            acc[m][n] = (f32x4){0.f, 0.f, 0.f, 0.f};

#pragma unroll
    for (int k0 = 0; k0 < 4; ++k0) {
        bf16x8 a[4], b[2];
#pragma unroll
        for (int m = 0; m < 4; ++m) {
            int ra = 16 * m + llo;
            int byte = (ra * 256 + (k0 * 32 + lhi * 8) * 2) ^ ((ra & 7) << 4);
            a[m] = *reinterpret_cast<const bf16x8*>(lds_raw + byte);
        }
#pragma unroll
        for (int n = 0; n < 2; ++n) {
            int col = wv * 32 + 16 * n + llo;
            b[n] = *reinterpret_cast<const bf16x8*>(WtU + (size_t)col * 128 + k0 * 32 + lhi * 8);
        }
#pragma unroll
        for (int m = 0; m < 4; ++m)
#pragma unroll
            for (int n = 0; n < 2; ++n)
                acc[m][n] = __builtin_amdgcn_mfma_f32_16x16x32_bf16(a[m], b[n], acc[m][n], 0, 0, 0);
    }

#pragma unroll
    for (int m = 0; m < 4; ++m) {
        int rbase = 16 * m + lhi * 4;
#pragma unroll
        for (int r = 0; r < 4; ++r) {
            int i = nb + rbase + r;
            if (i < N_NODES) {
#pragma unroll
                for (int n = 0; n < 2; ++n) {
                    int c = wv * 32 + 16 * n + llo;
                    out[(size_t)i * 128 + c] =
                        nodef[(size_t)i * 128 + c]
                        + fmaxf(acc[m][n][r] + b_upd[c], 0.f);
                }
            }
        }
    }
}

// ===========================================================================
extern "C" void kernel_launch(void* const* d_in, const int* in_sizes, int n_in,
                              void* d_out, int out_size, void* d_ws, size_t ws_size,
                              hipStream_t stream) {
    const float* nodef    = (const float*)d_in[0];
    const float* edgef    = (const float*)d_in[1];
    const int*   from_idx = (const int*)d_in[2];
    const int*   to_idx   = (const int*)d_in[3];
    const float* Wmsg     = (const float*)d_in[4];
    const float* bmsg     = (const float*)d_in[5];
    const float* Wrev     = (const float*)d_in[6];
    const float* brev     = (const float*)d_in[7];
    const float* Wupd     = (const float*)d_in[8];
    const float* bupd     = (const float*)d_in[9];
    float* out = (float*)d_out;
    char* ws = (char*)d_ws;

    unsigned int* A_u      = (unsigned int*)ws;               // 102,400,000
    unsigned int* msgs_u   = (unsigned int*)(ws + 102400000); // 163,840,000
    bf16_t*       Wt1      = (bf16_t*)(ws + 266240000);       // 131,072
    bf16_t*       WtE      = (bf16_t*)(ws + 266371072);       // 65,536
    bf16_t*       WtU      = (bf16_t*)(ws + 266436608);       // 32,768
    int*          hist     = (int*)(ws + 266469376);          // 400,000
    int*          cursor   = (int*)(ws + 266869376);          // 400,000
    int*          rowstart = (int*)(ws + 267269376);          // 400,016
    int*          inv      = (int*)(ws + 267669392);          // 2,560,000
    int*          bsum     = (int*)(ws + 270229392);          // 400
    int*          bbase    = (int*)(ws + 270229792);          // 400

    hipMemsetAsync(hist, 0, (size_t)N_NODES * sizeof(int), stream);
    prep_w_new<<<256, 256, 0, stream>>>(Wmsg, Wrev, Wupd, Wt1, WtE, WtU);
    hist_kernel<<<(N_EDGES + 255) / 256, 256, 0, stream>>>(to_idx, hist);
    scan_reduce_kernel<<<100, 1024, 0, stream>>>(hist, bsum);
    scan_base_kernel<<<1, 128, 0, stream>>>(bsum, bbase);
    scan_final_kernel<<<100, 1024, 0, stream>>>(hist, bbase, cursor, rowstart);
    inv_scatter_kernel<<<(N_EDGES + 255) / 256, 256, 0, stream>>>(to_idx, cursor, inv);
    proj_node_kernel<<<dim3((N_NODES + 63) / 64, 2), 512, 0, stream>>>(nodef, Wt1, A_u);
    edge_fused_kernel<<<N_EDGES / 128, 256, 0, stream>>>(
        edgef, from_idx, to_idx, inv, A_u, WtE, bmsg, brev, msgs_u);
    node_upd_kernel<<<(N_NODES + 63) / 64, 256, 0, stream>>>(
        msgs_u, rowstart, nodef, WtU, bupd, out);
}